// Round 3
// baseline (1110.880 us; speedup 1.0000x reference)
//
#include <hip/hip_runtime.h>
#include <hip/hip_bf16.h>

#define NEG_SLOPE 0.2f
#define LOG2E 1.44269504f

typedef __attribute__((ext_vector_type(8))) short short8;
typedef __attribute__((ext_vector_type(4))) float f32x4;

__device__ __forceinline__ unsigned short f2bf(float x) {
    unsigned u = __float_as_uint(x);
    unsigned r = (u + 0x7FFFu + ((u >> 16) & 1u)) >> 16;  // RNE
    return (unsigned short)r;
}

__device__ __forceinline__ float fexp2(float x) {
    return __builtin_amdgcn_exp2f(x);  // v_exp_f32: 2^x
}

__device__ __forceinline__ float readlane_f(float v, int l) {
    return __int_as_float(__builtin_amdgcn_readlane(__float_as_int(v), l));
}

// ========== CSR build: deg count + scan + bucketed packed scatter ==========
// Buckets are 64 nodes (d>>6). Stage-1 scatter frontier = nbuck cursors
// (L2-resident); stage-2 sort = 1 block/bucket, cursors seeded from row_ptr.

__global__ __launch_bounds__(256) void deg_count_k(
    const int* __restrict__ dsts, int* __restrict__ deg, int E) {
    int tid = blockIdx.x * 256 + threadIdx.x;
    int stride = gridDim.x * 256;
    int nq = E >> 2;
    const int4* d4p = (const int4*)dsts;
    for (int i = tid; i < nq; i += stride) {
        int4 d = d4p[i];
        atomicAdd(&deg[d.x], 1);
        atomicAdd(&deg[d.y], 1);
        atomicAdd(&deg[d.z], 1);
        atomicAdd(&deg[d.w], 1);
    }
    for (int e = (nq << 2) + tid; e < E; e += stride)
        atomicAdd(&deg[dsts[e]], 1);
}

// per-256-node block sums (deg + 1 self-loop each)
__global__ __launch_bounds__(256) void scan_part_k(
    const int* __restrict__ deg, int* __restrict__ bsum, int N) {
    int b = blockIdx.x;
    int n = b * 256 + threadIdx.x;
    int v = (n < N) ? deg[n] + 1 : 0;
    #pragma unroll
    for (int off = 32; off > 0; off >>= 1) v += __shfl_xor(v, off);
    __shared__ int wsum[4];
    int lane = threadIdx.x & 63, wave = threadIdx.x >> 6;
    if (lane == 0) wsum[wave] = v;
    __syncthreads();
    if (threadIdx.x == 0)
        bsum[b] = wsum[0] + wsum[1] + wsum[2] + wsum[3];
}

// 1-block exclusive scan of block sums (NB <= 512)
__global__ __launch_bounds__(512) void scan_top_k(
    const int* __restrict__ bsum, int* __restrict__ bbase,
    int* __restrict__ row_ptr, int NB, int N, int Etot) {
    __shared__ int tmp[512];
    int t = threadIdx.x;
    int v = (t < NB) ? bsum[t] : 0;
    tmp[t] = v;
    __syncthreads();
    for (int off = 1; off < 512; off <<= 1) {
        int x = (t >= off) ? tmp[t - off] : 0;
        __syncthreads();
        tmp[t] += x;
        __syncthreads();
    }
    if (t < NB) bbase[t] = tmp[t] - v;
    if (t == 0) row_ptr[N] = Etot;
}

// write row_ptr, pre-place self-loop at slot 0
__global__ __launch_bounds__(256) void scan_write_k(
    const int* __restrict__ deg, const int* __restrict__ bbase,
    int* __restrict__ row_ptr, int* __restrict__ csr_src, int N) {
    __shared__ int tmp[256];
    int b = blockIdx.x;
    int t = threadIdx.x;
    int n = b * 256 + t;
    int v = (n < N) ? deg[n] + 1 : 0;
    tmp[t] = v;
    __syncthreads();
    for (int off = 1; off < 256; off <<= 1) {
        int x = (t >= off) ? tmp[t - off] : 0;
        __syncthreads();
        tmp[t] += x;
        __syncthreads();
    }
    if (n < N) {
        int rp = bbase[b] + tmp[t] - v;
        row_ptr[n] = rp;
        csr_src[rp] = n;   // self-loop
    }
}

// bptr/bcur init: bucket b's region starts at row_ptr[b*64]
__global__ __launch_bounds__(256) void bptr_init_k(
    const int* __restrict__ row_ptr, int* __restrict__ bptr,
    int* __restrict__ bcur, int nbuck) {
    int b = blockIdx.x * 256 + threadIdx.x;
    if (b < nbuck) {
        int v = row_ptr[b << 6];
        bptr[b] = v;
        bcur[b] = v;
    }
}

// stage 1: packed scatter into bucket segments (frontier = nbuck lines)
__global__ __launch_bounds__(256) void bscatter_k(
    const int* __restrict__ srcs, const int* __restrict__ dsts,
    int* __restrict__ bcur, int* __restrict__ pairs, int E) {
    int tid = blockIdx.x * 256 + threadIdx.x;
    int stride = gridDim.x * 256;
    int nq = E >> 2;
    const int4* s4p = (const int4*)srcs;
    const int4* d4p = (const int4*)dsts;
    for (int i = tid; i < nq; i += stride) {
        int4 s = s4p[i];
        int4 d = d4p[i];
        int p0 = atomicAdd(&bcur[d.x >> 6], 1);
        int p1 = atomicAdd(&bcur[d.y >> 6], 1);
        int p2 = atomicAdd(&bcur[d.z >> 6], 1);
        int p3 = atomicAdd(&bcur[d.w >> 6], 1);
        pairs[p0] = (s.x << 6) | (d.x & 63);
        pairs[p1] = (s.y << 6) | (d.y & 63);
        pairs[p2] = (s.z << 6) | (d.z & 63);
        pairs[p3] = (s.w << 6) | (d.w & 63);
    }
    for (int e = (nq << 2) + tid; e < E; e += stride) {
        int s = srcs[e], d = dsts[e];
        int p = atomicAdd(&bcur[d >> 6], 1);
        pairs[p] = (s << 6) | (d & 63);
    }
}

// stage 2: per-bucket sort, LDS cursors seeded from row_ptr (no hist/scan)
__global__ __launch_bounds__(256) void bucket_sort_k(
    const int* __restrict__ pairs, const int* __restrict__ bptr,
    const int* __restrict__ bcur, const int* __restrict__ row_ptr,
    int* __restrict__ csr_src, int N) {
    __shared__ int lcur[64];
    int b = blockIdx.x;
    int n0 = b << 6;
    int t = threadIdx.x;
    if (t < 64) {
        int n = n0 + t;
        lcur[t] = (n < N) ? row_ptr[n] + 1 : 0;  // +1: self-loop at slot 0
    }
    __syncthreads();
    int e0 = bptr[b], e1 = bcur[b];
    for (int e = e0 + t; e < e1; e += 256) {
        int p = pairs[e];
        int pos = atomicAdd(&lcur[p & 63], 1);
        csr_src[pos] = p >> 6;
    }
}

// ====== fused MFMA GEMM + pack (COUT=64): x[N,K] @ W[K,64] -> hrec/asb/adb ==
// hrec: 128 B/node bf16 h (head-major 16B blocks); asb/adb: N*8 floats

template <int K>
__global__ __launch_bounds__(256) void gemm_pack8_k(
    const float* __restrict__ x, const float* __restrict__ W,
    const float* __restrict__ a_src, const float* __restrict__ a_dst,
    char* __restrict__ hrec, float* __restrict__ asb,
    float* __restrict__ adb, int N) {
    constexpr int NT = 4;
    constexpr int KT = K / 32;
    constexpr size_t WF_BYTES = (size_t)KT * NT * 64 * 8 * sizeof(short);
    constexpr size_t H_BYTES = (size_t)64 * 65 * sizeof(float);
    __shared__ alignas(16) char smem[WF_BYTES > H_BYTES ? WF_BYTES : H_BYTES];
    short* Wf = (short*)smem;
    float* hL = (float*)smem;
    int tid = threadIdx.x;
    for (int f = tid; f < KT * NT * 64; f += 256) {
        int lane = f & 63;
        int ntk = f >> 6;
        int nt = ntk % NT, kt = ntk / NT;
        int q = lane >> 4, c = lane & 15;
        int n = nt * 16 + c;
        int k0 = kt * 32 + q * 8;
        short8 frag;
        #pragma unroll
        for (int j = 0; j < 8; ++j)
            frag[j] = (short)f2bf(W[(size_t)(k0 + j) * 64 + n]);
        *(short8*)&Wf[f * 8] = frag;
    }
    __syncthreads();
    int wave = tid >> 6, lane = tid & 63;
    int q = lane >> 4, c = lane & 15;
    int m0 = blockIdx.x * 64 + wave * 16;
    int arow = m0 + c;
    int arl = arow < N ? arow : N - 1;
    f32x4 acc[NT] = {};
    for (int kt = 0; kt < KT; ++kt) {
        const float* xp = x + (size_t)arl * K + kt * 32 + q * 8;
        float4 a0 = *(const float4*)xp;
        float4 a1 = *(const float4*)(xp + 4);
        float av[8] = {a0.x, a0.y, a0.z, a0.w, a1.x, a1.y, a1.z, a1.w};
        short8 af;
        #pragma unroll
        for (int j = 0; j < 8; ++j) af[j] = (short)f2bf(av[j]);
        #pragma unroll
        for (int nt = 0; nt < NT; ++nt) {
            short8 bf = *(const short8*)&Wf[((kt * NT + nt) * 64 + lane) * 8];
            acc[nt] = __builtin_amdgcn_mfma_f32_16x16x32_bf16(af, bf, acc[nt],
                                                              0, 0, 0);
        }
    }
    __syncthreads();  // all waves done reading Wf; reuse as hL
    int lrow = wave * 16 + q * 4;
    #pragma unroll
    for (int nt = 0; nt < NT; ++nt)
        #pragma unroll
        for (int reg = 0; reg < 4; ++reg)
            hL[(lrow + reg) * 65 + nt * 16 + c] = acc[nt][reg];
    __syncthreads();
    #pragma unroll
    for (int it = 0; it < 2; ++it) {
        int id = it * 256 + tid;  // 0..511 = (node 0..63) x (head 0..7)
        int ln = id >> 3, hd = id & 7;
        int gn = blockIdx.x * 64 + ln;
        if (gn >= N) continue;
        const float* hp = &hL[ln * 65 + hd * 8];
        float as = 0.f, ad = 0.f;
        float hv[8];
        #pragma unroll
        for (int j = 0; j < 8; ++j) {
            hv[j] = hp[j];
            as += hv[j] * a_src[hd * 8 + j];
            ad += hv[j] * a_dst[hd * 8 + j];
        }
        adb[gn * 8 + hd] = ad * LOG2E;
        asb[gn * 8 + hd] = as * LOG2E;
        unsigned short u[8];
        #pragma unroll
        for (int j = 0; j < 8; ++j) u[j] = f2bf(hv[j]);
        uint4 pk;
        pk.x = (unsigned)u[0] | ((unsigned)u[1] << 16);
        pk.y = (unsigned)u[2] | ((unsigned)u[3] << 16);
        pk.z = (unsigned)u[4] | ((unsigned)u[5] << 16);
        pk.w = (unsigned)u[6] | ((unsigned)u[7] << 16);
        *(uint4*)(hrec + (size_t)gn * 128 + hd * 16) = pk;
    }
}

// ====== fused MFMA GEMM + pack40 (layer 2, COUT=40) -> 80 B records ======

__global__ __launch_bounds__(256) void gemm_pack40_k(
    const float* __restrict__ x, const float* __restrict__ W,
    const float* __restrict__ a_src, const float* __restrict__ a_dst,
    char* __restrict__ h40, float* __restrict__ asb40,
    float* __restrict__ adb, int N) {
    constexpr int K = 64, NT = 3, KT = 2;
    constexpr size_t WF_BYTES = (size_t)KT * NT * 64 * 8 * sizeof(short);
    constexpr size_t H_BYTES = (size_t)64 * 41 * sizeof(float);
    __shared__ alignas(16) char smem[WF_BYTES > H_BYTES ? WF_BYTES : H_BYTES];
    short* Wf = (short*)smem;
    float* hL = (float*)smem;
    int tid = threadIdx.x;
    for (int f = tid; f < KT * NT * 64; f += 256) {
        int lane = f & 63;
        int ntk = f >> 6;
        int nt = ntk % NT, kt = ntk / NT;
        int q = lane >> 4, c = lane & 15;
        int n = nt * 16 + c;
        int k0 = kt * 32 + q * 8;
        short8 frag;
        #pragma unroll
        for (int j = 0; j < 8; ++j) {
            float v = (n < 40) ? W[(size_t)(k0 + j) * 40 + n] : 0.f;
            frag[j] = (short)f2bf(v);
        }
        *(short8*)&Wf[f * 8] = frag;
    }
    __syncthreads();
    int wave = tid >> 6, lane = tid & 63;
    int q = lane >> 4, c = lane & 15;
    int m0 = blockIdx.x * 64 + wave * 16;
    int arow = m0 + c;
    int arl = arow < N ? arow : N - 1;
    f32x4 acc[NT] = {};
    for (int kt = 0; kt < KT; ++kt) {
        const float* xp = x + (size_t)arl * K + kt * 32 + q * 8;
        float4 a0 = *(const float4*)xp;
        float4 a1 = *(const float4*)(xp + 4);
        float av[8] = {a0.x, a0.y, a0.z, a0.w, a1.x, a1.y, a1.z, a1.w};
        short8 af;
        #pragma unroll
        for (int j = 0; j < 8; ++j) af[j] = (short)f2bf(av[j]);
        #pragma unroll
        for (int nt = 0; nt < NT; ++nt) {
            short8 bf = *(const short8*)&Wf[((kt * NT + nt) * 64 + lane) * 8];
            acc[nt] = __builtin_amdgcn_mfma_f32_16x16x32_bf16(af, bf, acc[nt],
                                                              0, 0, 0);
        }
    }
    __syncthreads();
    int lrow = wave * 16 + q * 4;
    #pragma unroll
    for (int nt = 0; nt < NT; ++nt) {
        int n = nt * 16 + c;
        if (n >= 40) continue;
        #pragma unroll
        for (int reg = 0; reg < 4; ++reg)
            hL[(lrow + reg) * 41 + n] = acc[nt][reg];
    }
    __syncthreads();
    // 4 threads per node compute pas/pad
    int ln = tid >> 2, sub = tid & 3;
    int gn = blockIdx.x * 64 + ln;
    float pas = 0.f, pad = 0.f;
    if (gn < N) {
        for (int j = sub; j < 40; j += 4) {
            float hv = hL[ln * 41 + j];
            pas += hv * a_src[j];
            pad += hv * a_dst[j];
        }
    }
    pas += __shfl_xor(pas, 1); pas += __shfl_xor(pas, 2);
    pad += __shfl_xor(pad, 1); pad += __shfl_xor(pad, 2);
    if (gn < N && sub == 0) {
        asb40[gn] = pas * LOG2E;
        adb[gn] = pad * LOG2E;
    }
    // write bf16 h, stride 80 B
    for (int i = tid; i < 64 * 40; i += 256) {
        int n2 = i / 40, ch = i % 40;
        int g2 = blockIdx.x * 64 + n2;
        if (g2 < N)
            *(unsigned short*)(h40 + (size_t)g2 * 80 + ch * 2) =
                f2bf(hL[n2 * 41 + ch]);
    }
}

// ======= aggr64: parallel weight phase (8 exp / 64 edges) + LDS broadcast ===

#define EDGE64(SUF, IDX)                                                     \
    int s##SUF = __builtin_amdgcn_readlane(sv, (IDX));                       \
    float w##SUF = lwp[(IDX)];                                               \
    unsigned u##SUF =                                                        \
        *(const unsigned short*)(hrec + (size_t)s##SUF * 128 + lane2);

__global__ __launch_bounds__(256) void aggr64_k(
    const char* __restrict__ hrec, const float* __restrict__ asb,
    const float* __restrict__ adb, const int* __restrict__ row_ptr,
    const int* __restrict__ csr_src, const float* __restrict__ bias,
    float* __restrict__ out, int N) {
    __shared__ float wlds[4 * 1040];  // 4 waves x 2 buffers x (8*65)
    int wave = threadIdx.x >> 6;
    int node = blockIdx.x * 4 + wave;
    if (node >= N) return;
    int lane = threadIdx.x & 63;
    int hd = lane >> 3;
    int lane2 = lane * 2;
    float* wbA = wlds + wave * 1040;
    float* wbB = wbA + 520;
    const float* lwpA = wbA + hd * 65;
    const float* lwpB = wbB + hd * 65;
    int beg = row_ptr[node], end = row_ptr[node + 1];
    float4 adv0 = *(const float4*)(adb + (size_t)node * 8);
    float4 adv1 = *(const float4*)(adb + (size_t)node * 8 + 4);
    float acc0 = 0.f, acc1 = 0.f, acc2 = 0.f, acc3 = 0.f;
    float acc4 = 0.f, acc5 = 0.f, acc6 = 0.f, acc7 = 0.f;
    float l0 = 0.f, l1 = 0.f, l2 = 0.f, l3 = 0.f;
    float l4 = 0.f, l5 = 0.f, l6 = 0.f, l7 = 0.f;
    int par = 0;
    for (int i0 = beg; i0 < end; i0 += 64, par ^= 1) {
        int tail = end - i0;
        int sv = csr_src[i0 + (lane < tail ? lane : 0)];
        int cnt = tail < 64 ? tail : 64;
        float* wb = par ? wbB : wbA;
        const float* lwp = par ? lwpB : lwpA;
        // ---- parallel weight phase: this lane's edge, all 8 heads ----
        {
            const float* asp = asb + (size_t)sv * 8;
            float4 s0 = *(const float4*)asp;
            float4 s1 = *(const float4*)(asp + 4);
            float w0 = s0.x + adv0.x; w0 = fmaxf(w0, NEG_SLOPE * w0); w0 = fexp2(w0);
            float w1 = s0.y + adv0.y; w1 = fmaxf(w1, NEG_SLOPE * w1); w1 = fexp2(w1);
            float w2 = s0.z + adv0.z; w2 = fmaxf(w2, NEG_SLOPE * w2); w2 = fexp2(w2);
            float w3 = s0.w + adv0.w; w3 = fmaxf(w3, NEG_SLOPE * w3); w3 = fexp2(w3);
            float w4 = s1.x + adv1.x; w4 = fmaxf(w4, NEG_SLOPE * w4); w4 = fexp2(w4);
            float w5 = s1.y + adv1.y; w5 = fmaxf(w5, NEG_SLOPE * w5); w5 = fexp2(w5);
            float w6 = s1.z + adv1.z; w6 = fmaxf(w6, NEG_SLOPE * w6); w6 = fexp2(w6);
            float w7 = s1.w + adv1.w; w7 = fmaxf(w7, NEG_SLOPE * w7); w7 = fexp2(w7);
            wb[lane]       = w0;
            wb[65 + lane]  = w1;
            wb[130 + lane] = w2;
            wb[195 + lane] = w3;
            wb[260 + lane] = w4;
            wb[325 + lane] = w5;
            wb[390 + lane] = w6;
            wb[455 + lane] = w7;
        }
        // ---- fma phase: w via LDS broadcast, u via readlane'd base ----
        int j = 0;
        for (; j + 8 <= cnt; j += 8) {
            EDGE64(A, j)      EDGE64(B, j + 1) EDGE64(C, j + 2) EDGE64(D, j + 3)
            EDGE64(E2, j + 4) EDGE64(F, j + 5) EDGE64(G, j + 6) EDGE64(H2, j + 7)
            l0 += wA; l1 += wB; l2 += wC; l3 += wD;
            l4 += wE2; l5 += wF; l6 += wG; l7 += wH2;
            acc0 = fmaf(wA, __uint_as_float(uA << 16), acc0);
            acc1 = fmaf(wB, __uint_as_float(uB << 16), acc1);
            acc2 = fmaf(wC, __uint_as_float(uC << 16), acc2);
            acc3 = fmaf(wD, __uint_as_float(uD << 16), acc3);
            acc4 = fmaf(wE2, __uint_as_float(uE2 << 16), acc4);
            acc5 = fmaf(wF, __uint_as_float(uF << 16), acc5);
            acc6 = fmaf(wG, __uint_as_float(uG << 16), acc6);
            acc7 = fmaf(wH2, __uint_as_float(uH2 << 16), acc7);
        }
        for (; j + 4 <= cnt; j += 4) {
            EDGE64(A, j) EDGE64(B, j + 1) EDGE64(C, j + 2) EDGE64(D, j + 3)
            l0 += wA; l1 += wB; l2 += wC; l3 += wD;
            acc0 = fmaf(wA, __uint_as_float(uA << 16), acc0);
            acc1 = fmaf(wB, __uint_as_float(uB << 16), acc1);
            acc2 = fmaf(wC, __uint_as_float(uC << 16), acc2);
            acc3 = fmaf(wD, __uint_as_float(uD << 16), acc3);
        }
        for (; j < cnt; ++j) {
            EDGE64(A, j)
            l0 += wA;
            acc0 = fmaf(wA, __uint_as_float(uA << 16), acc0);
        }
    }
    float l = ((l0 + l1) + (l2 + l3)) + ((l4 + l5) + (l6 + l7));
    float acc = ((acc0 + acc1) + (acc2 + acc3)) + ((acc4 + acc5) + (acc6 + acc7));
    out[(size_t)node * 64 + lane] = acc / (l + 1e-16f) + bias[lane];
}

// ======= aggr40: parallel weight phase (1 exp / 64 edges) + readlane fma ====

#define F40(SUF, IDX)                                                        \
    int s##SUF = __builtin_amdgcn_readlane(sv, (IDX));                       \
    float w##SUF = readlane_f(wv, (IDX));                                    \
    unsigned u##SUF =                                                        \
        *(const unsigned short*)(hrec + (size_t)s##SUF * 80 + cl2);

__global__ __launch_bounds__(256) void aggr40_k(
    const char* __restrict__ hrec, const float* __restrict__ asb,
    const float* __restrict__ adb, const int* __restrict__ row_ptr,
    const int* __restrict__ csr_src, const float* __restrict__ bias,
    float* __restrict__ out, int N) {
    int node = blockIdx.x * 4 + (threadIdx.x >> 6);
    if (node >= N) return;
    int lane = threadIdx.x & 63;
    int cl2 = (lane < 40 ? lane : 0) * 2;
    int beg = row_ptr[node], end = row_ptr[node + 1];
    float ad = adb[node];
    float acc0 = 0.f, acc1 = 0.f, acc2 = 0.f, acc3 = 0.f;
    float acc4 = 0.f, acc5 = 0.f, acc6 = 0.f, acc7 = 0.f;
    float lpart = 0.f;
    for (int i0 = beg; i0 < end; i0 += 64) {
        int tail = end - i0;
        int sv = csr_src[i0 + (lane < tail ? lane : 0)];
        int cnt = tail < 64 ? tail : 64;
        // ---- parallel weight phase: lane computes its own edge's weight ----
        float as = asb[sv];
        float v = as + ad;
        v = fmaxf(v, NEG_SLOPE * v);
        float wv = fexp2(v);
        wv = (lane < cnt) ? wv : 0.f;
        lpart += wv;
        // ---- fma phase: branch-free, weights via readlane ----
        int j = 0;
        for (; j + 8 <= cnt; j += 8) {
            F40(A, j)     F40(B, j + 1) F40(C, j + 2) F40(D, j + 3)
            F40(E2, j + 4) F40(F, j + 5) F40(G, j + 6) F40(H2, j + 7)
            acc0 = fmaf(wA, __uint_as_float(uA << 16), acc0);
            acc1 = fmaf(wB, __uint_as_float(uB << 16), acc1);
            acc2 = fmaf(wC, __uint_as_float(uC << 16), acc2);
            acc3 = fmaf(wD, __uint_as_float(uD << 16), acc3);
            acc4 = fmaf(wE2, __uint_as_float(uE2 << 16), acc4);
            acc5 = fmaf(wF, __uint_as_float(uF << 16), acc5);
            acc6 = fmaf(wG, __uint_as_float(uG << 16), acc6);
            acc7 = fmaf(wH2, __uint_as_float(uH2 << 16), acc7);
        }
        for (; j + 4 <= cnt; j += 4) {
            F40(A, j) F40(B, j + 1) F40(C, j + 2) F40(D, j + 3)
            acc0 = fmaf(wA, __uint_as_float(uA << 16), acc0);
            acc1 = fmaf(wB, __uint_as_float(uB << 16), acc1);
            acc2 = fmaf(wC, __uint_as_float(uC << 16), acc2);
            acc3 = fmaf(wD, __uint_as_float(uD << 16), acc3);
        }
        for (; j < cnt; ++j) {
            F40(A, j)
            acc0 = fmaf(wA, __uint_as_float(uA << 16), acc0);
        }
    }
    // reduce l across all lanes (each lane holds partial sum of its edges)
    #pragma unroll
    for (int off = 32; off > 0; off >>= 1) lpart += __shfl_xor(lpart, off);
    float l = lpart;
    float acc = ((acc0 + acc1) + (acc2 + acc3)) + ((acc4 + acc5) + (acc6 + acc7));
    // fused bias + log_softmax over the 40 class lanes
    float val = acc / (l + 1e-16f) + ((lane < 40) ? bias[lane] : 0.f);
    float mval = (lane < 40) ? val : -1e30f;
    #pragma unroll
    for (int off = 32; off > 0; off >>= 1)
        mval = fmaxf(mval, __shfl_xor(mval, off));
    float ex = (lane < 40) ? __expf(val - mval) : 0.f;
    #pragma unroll
    for (int off = 32; off > 0; off >>= 1) ex += __shfl_xor(ex, off);
    if (lane < 40)
        out[(size_t)node * 40 + lane] = val - mval - __logf(ex);
}

// =================== launch ===================

extern "C" void kernel_launch(void* const* d_in, const int* in_sizes, int n_in,
                              void* d_out, int out_size, void* d_ws,
                              size_t ws_size, hipStream_t stream) {
    const float* features = (const float*)d_in[0];
    const int* edge_index = (const int*)d_in[1];
    const float* W0 = (const float*)d_in[2];
    const float* as0 = (const float*)d_in[3];
    const float* ad0 = (const float*)d_in[4];
    const float* b0 = (const float*)d_in[5];
    const float* W1 = (const float*)d_in[6];
    const float* as1 = (const float*)d_in[7];
    const float* ad1 = (const float*)d_in[8];
    const float* b1 = (const float*)d_in[9];
    const float* W2 = (const float*)d_in[10];
    const float* as2 = (const float*)d_in[11];
    const float* ad2 = (const float*)d_in[12];
    const float* b2 = (const float*)d_in[13];

    int N = in_sizes[0] / 256;
    int E = in_sizes[1] / 2;
    int Etot = E + N;
    int NB = (N + 255) >> 8;       // 256-node blocks for scan (<= 512)
    int nbuck = (N + 63) >> 6;     // 64-node buckets for scatter/sort
    const int* srcs = edge_index;
    const int* dsts = edge_index + E;

    // workspace layout
    float* ws = (float*)d_ws;
    float* Hbuf = ws;                              // N*64 floats (pairs scratch)
    float* Abuf = Hbuf + (size_t)N * 64;           // N*64 floats
    float* adb  = Abuf + (size_t)N * 64;           // N*8
    float* asb  = adb + (size_t)N * 8;             // N*8
    char* hrec  = (char*)(asb + (size_t)N * 8);    // N*128 bytes
    int* row_ptr = (int*)(hrec + (size_t)N * 128); // N+1
    int* deg     = row_ptr + (N + 2);              // N
    int* bsum    = deg + N;                        // 512
    int* bbase   = bsum + 512;                     // 512
    int* bptr    = bbase + 512;                    // nbuck
    int* bcur    = bptr + nbuck;                   // nbuck
    int* csr_src = bcur + nbuck;                   // Etot
    int* pairs   = (int*)Hbuf;                     // scratch, dead before gemm

    const int B = 256;
    int gAg = (N + 3) / 4;
    int gGm = (N + 63) / 64;
    int nq = (E + 3) >> 2;
    int gEd = (nq + 255) / 256;
    if (gEd > 8192) gEd = 8192;
    int gBp = (nbuck + 255) / 256;

    // ---------- CSR build ----------
    (void)hipMemsetAsync(deg, 0, (size_t)N * 4, stream);
    deg_count_k<<<gEd, B, 0, stream>>>(dsts, deg, E);
    scan_part_k<<<NB, B, 0, stream>>>(deg, bsum, N);
    scan_top_k<<<1, 512, 0, stream>>>(bsum, bbase, row_ptr, NB, N, Etot);
    scan_write_k<<<NB, B, 0, stream>>>(deg, bbase, row_ptr, csr_src, N);
    bptr_init_k<<<gBp, B, 0, stream>>>(row_ptr, bptr, bcur, nbuck);
    bscatter_k<<<gEd, B, 0, stream>>>(srcs, dsts, bcur, pairs, E);
    bucket_sort_k<<<nbuck, B, 0, stream>>>(pairs, bptr, bcur, row_ptr,
                                           csr_src, N);

    // ---------------- layer 0 ----------------
    gemm_pack8_k<256><<<gGm, B, 0, stream>>>(features, W0, as0, ad0, hrec,
                                             asb, adb, N);
    aggr64_k<<<gAg, B, 0, stream>>>(hrec, asb, adb, row_ptr, csr_src, b0,
                                    Abuf, N);

    // ---------------- layer 1 ----------------
    gemm_pack8_k<64><<<gGm, B, 0, stream>>>(Abuf, W1, as1, ad1, hrec, asb,
                                            adb, N);
    aggr64_k<<<gAg, B, 0, stream>>>(hrec, asb, adb, row_ptr, csr_src, b1,
                                    Abuf, N);

    // ---------------- layer 2 ----------------
    gemm_pack40_k<<<gGm, B, 0, stream>>>(Abuf, W2, as2, ad2, hrec, asb, adb,
                                         N);
    aggr40_k<<<gAg, B, 0, stream>>>(hrec, asb, adb, row_ptr, csr_src, b2,
                                    (float*)d_out, N);
}

// Round 4
// 766.732 us; speedup vs baseline: 1.4488x; 1.4488x over previous
//
#include <hip/hip_runtime.h>
#include <hip/hip_bf16.h>

#define NEG_SLOPE 0.2f
#define LOG2E 1.44269504f
#define EPB 4096      // edges per scatter block
#define MAXBUCK 1600  // >= ceil(N/64)

typedef __attribute__((ext_vector_type(8))) short short8;
typedef __attribute__((ext_vector_type(4))) float f32x4;

__device__ __forceinline__ unsigned short f2bf(float x) {
    unsigned u = __float_as_uint(x);
    unsigned r = (u + 0x7FFFu + ((u >> 16) & 1u)) >> 16;  // RNE
    return (unsigned short)r;
}

__device__ __forceinline__ float fexp2(float x) {
    return __builtin_amdgcn_exp2f(x);  // v_exp_f32: 2^x
}

__device__ __forceinline__ float readlane_f(float v, int l) {
    return __int_as_float(__builtin_amdgcn_readlane(__float_as_int(v), l));
}

// ========== CSR build: deg count + scan + LDS-aggregated bucket scatter =====

__global__ __launch_bounds__(256) void deg_count_k(
    const int* __restrict__ dsts, int* __restrict__ deg, int E) {
    int tid = blockIdx.x * 256 + threadIdx.x;
    int stride = gridDim.x * 256;
    int nq = E >> 2;
    const int4* d4p = (const int4*)dsts;
    for (int i = tid; i < nq; i += stride) {
        int4 d = d4p[i];
        atomicAdd(&deg[d.x], 1);
        atomicAdd(&deg[d.y], 1);
        atomicAdd(&deg[d.z], 1);
        atomicAdd(&deg[d.w], 1);
    }
    for (int e = (nq << 2) + tid; e < E; e += stride)
        atomicAdd(&deg[dsts[e]], 1);
}

// per-256-node block sums (deg + 1 self-loop each)
__global__ __launch_bounds__(256) void scan_part_k(
    const int* __restrict__ deg, int* __restrict__ bsum, int N) {
    int b = blockIdx.x;
    int n = b * 256 + threadIdx.x;
    int v = (n < N) ? deg[n] + 1 : 0;
    #pragma unroll
    for (int off = 32; off > 0; off >>= 1) v += __shfl_xor(v, off);
    __shared__ int wsum[4];
    int lane = threadIdx.x & 63, wave = threadIdx.x >> 6;
    if (lane == 0) wsum[wave] = v;
    __syncthreads();
    if (threadIdx.x == 0)
        bsum[b] = wsum[0] + wsum[1] + wsum[2] + wsum[3];
}

// 1-block exclusive scan of block sums (NB <= 512)
__global__ __launch_bounds__(512) void scan_top_k(
    const int* __restrict__ bsum, int* __restrict__ bbase,
    int* __restrict__ row_ptr, int NB, int N, int Etot) {
    __shared__ int tmp[512];
    int t = threadIdx.x;
    int v = (t < NB) ? bsum[t] : 0;
    tmp[t] = v;
    __syncthreads();
    for (int off = 1; off < 512; off <<= 1) {
        int x = (t >= off) ? tmp[t - off] : 0;
        __syncthreads();
        tmp[t] += x;
        __syncthreads();
    }
    if (t < NB) bbase[t] = tmp[t] - v;
    if (t == 0) row_ptr[N] = Etot;
}

// write row_ptr, pre-place self-loop at slot 0
__global__ __launch_bounds__(256) void scan_write_k(
    const int* __restrict__ deg, const int* __restrict__ bbase,
    int* __restrict__ row_ptr, int* __restrict__ csr_src, int N) {
    __shared__ int tmp[256];
    int b = blockIdx.x;
    int t = threadIdx.x;
    int n = b * 256 + t;
    int v = (n < N) ? deg[n] + 1 : 0;
    tmp[t] = v;
    __syncthreads();
    for (int off = 1; off < 256; off <<= 1) {
        int x = (t >= off) ? tmp[t - off] : 0;
        __syncthreads();
        tmp[t] += x;
        __syncthreads();
    }
    if (n < N) {
        int rp = bbase[b] + tmp[t] - v;
        row_ptr[n] = rp;
        csr_src[rp] = n;   // self-loop
    }
}

// bptrE[b]: start of bucket b's segment in pairs[] (self-loops excluded)
__global__ __launch_bounds__(256) void bptr_init_k(
    const int* __restrict__ row_ptr, int* __restrict__ bptrE,
    int* __restrict__ bcurE, int nbuck) {
    int b = blockIdx.x * 256 + threadIdx.x;
    if (b < nbuck) {
        int n = b << 6;
        int v = row_ptr[n] - n;  // subtract the n self-loop slots before n
        bptrE[b] = v;
        bcurE[b] = v;
    }
}

// LDS-aggregated packed scatter: 1 return-atomic per (block,bucket),
// run-contiguous pair writes (round-1-proven structure).
__global__ __launch_bounds__(256) void bscatter_k(
    const int* __restrict__ srcs, const int* __restrict__ dsts,
    int* __restrict__ bcurE, int* __restrict__ pairs, int E, int nbuck) {
    __shared__ int lh[MAXBUCK];
    __shared__ int lbase[MAXBUCK];
    int tid = threadIdx.x;
    for (int i = tid; i < nbuck; i += 256) lh[i] = 0;
    __syncthreads();
    int base = blockIdx.x * EPB;
    int cnt = E - base;
    if (cnt > EPB) cnt = EPB;
    int nq = cnt >> 2;
    const int4* d4p = (const int4*)(dsts + base);
    const int4* s4p = (const int4*)(srcs + base);
    for (int i = tid; i < nq; i += 256) {
        int4 d = d4p[i];
        atomicAdd(&lh[d.x >> 6], 1);
        atomicAdd(&lh[d.y >> 6], 1);
        atomicAdd(&lh[d.z >> 6], 1);
        atomicAdd(&lh[d.w >> 6], 1);
    }
    for (int i = (nq << 2) + tid; i < cnt; i += 256)
        atomicAdd(&lh[dsts[base + i] >> 6], 1);
    __syncthreads();
    for (int i = tid; i < nbuck; i += 256) {
        int c = lh[i];
        lbase[i] = c ? atomicAdd(&bcurE[i], c) : 0;
        lh[i] = 0;
    }
    __syncthreads();
    for (int i = tid; i < nq; i += 256) {
        int4 d = d4p[i];
        int4 s = s4p[i];
        int r0 = atomicAdd(&lh[d.x >> 6], 1);
        int r1 = atomicAdd(&lh[d.y >> 6], 1);
        int r2 = atomicAdd(&lh[d.z >> 6], 1);
        int r3 = atomicAdd(&lh[d.w >> 6], 1);
        pairs[lbase[d.x >> 6] + r0] = (s.x << 6) | (d.x & 63);
        pairs[lbase[d.y >> 6] + r1] = (s.y << 6) | (d.y & 63);
        pairs[lbase[d.z >> 6] + r2] = (s.z << 6) | (d.z & 63);
        pairs[lbase[d.w >> 6] + r3] = (s.w << 6) | (d.w & 63);
    }
    for (int i = (nq << 2) + tid; i < cnt; i += 256) {
        int s = srcs[base + i], d = dsts[base + i];
        int r = atomicAdd(&lh[d >> 6], 1);
        pairs[lbase[d >> 6] + r] = (s << 6) | (d & 63);
    }
}

// per-bucket sort into csr_src, LDS cursors seeded from row_ptr
__global__ __launch_bounds__(256) void bucket_sort_k(
    const int* __restrict__ pairs, const int* __restrict__ bptrE,
    const int* __restrict__ bcurE, const int* __restrict__ row_ptr,
    int* __restrict__ csr_src, int N) {
    __shared__ int lcur[64];
    int b = blockIdx.x;
    int n0 = b << 6;
    int t = threadIdx.x;
    if (t < 64) {
        int n = n0 + t;
        lcur[t] = (n < N) ? row_ptr[n] + 1 : 0;  // +1: self-loop at slot 0
    }
    __syncthreads();
    int e0 = bptrE[b], e1 = bcurE[b];
    for (int e = e0 + t; e < e1; e += 256) {
        int p = pairs[e];
        int pos = atomicAdd(&lcur[p & 63], 1);
        csr_src[pos] = p >> 6;
    }
}

// ====== fused MFMA GEMM + pack (COUT=64): x[N,K] @ W[K,64] -> hrec/asb/adb ==

template <int K>
__global__ __launch_bounds__(256) void gemm_pack8_k(
    const float* __restrict__ x, const float* __restrict__ W,
    const float* __restrict__ a_src, const float* __restrict__ a_dst,
    char* __restrict__ hrec, float* __restrict__ asb,
    float* __restrict__ adb, int N) {
    constexpr int NT = 4;
    constexpr int KT = K / 32;
    constexpr size_t WF_BYTES = (size_t)KT * NT * 64 * 8 * sizeof(short);
    constexpr size_t H_BYTES = (size_t)64 * 65 * sizeof(float);
    __shared__ alignas(16) char smem[WF_BYTES > H_BYTES ? WF_BYTES : H_BYTES];
    short* Wf = (short*)smem;
    float* hL = (float*)smem;
    int tid = threadIdx.x;
    for (int f = tid; f < KT * NT * 64; f += 256) {
        int lane = f & 63;
        int ntk = f >> 6;
        int nt = ntk % NT, kt = ntk / NT;
        int q = lane >> 4, c = lane & 15;
        int n = nt * 16 + c;
        int k0 = kt * 32 + q * 8;
        short8 frag;
        #pragma unroll
        for (int j = 0; j < 8; ++j)
            frag[j] = (short)f2bf(W[(size_t)(k0 + j) * 64 + n]);
        *(short8*)&Wf[f * 8] = frag;
    }
    __syncthreads();
    int wave = tid >> 6, lane = tid & 63;
    int q = lane >> 4, c = lane & 15;
    int m0 = blockIdx.x * 64 + wave * 16;
    int arow = m0 + c;
    int arl = arow < N ? arow : N - 1;
    f32x4 acc[NT] = {};
    for (int kt = 0; kt < KT; ++kt) {
        const float* xp = x + (size_t)arl * K + kt * 32 + q * 8;
        float4 a0 = *(const float4*)xp;
        float4 a1 = *(const float4*)(xp + 4);
        float av[8] = {a0.x, a0.y, a0.z, a0.w, a1.x, a1.y, a1.z, a1.w};
        short8 af;
        #pragma unroll
        for (int j = 0; j < 8; ++j) af[j] = (short)f2bf(av[j]);
        #pragma unroll
        for (int nt = 0; nt < NT; ++nt) {
            short8 bf = *(const short8*)&Wf[((kt * NT + nt) * 64 + lane) * 8];
            acc[nt] = __builtin_amdgcn_mfma_f32_16x16x32_bf16(af, bf, acc[nt],
                                                              0, 0, 0);
        }
    }
    __syncthreads();  // all waves done reading Wf; reuse as hL
    int lrow = wave * 16 + q * 4;
    #pragma unroll
    for (int nt = 0; nt < NT; ++nt)
        #pragma unroll
        for (int reg = 0; reg < 4; ++reg)
            hL[(lrow + reg) * 65 + nt * 16 + c] = acc[nt][reg];
    __syncthreads();
    #pragma unroll
    for (int it = 0; it < 2; ++it) {
        int id = it * 256 + tid;  // 0..511 = (node 0..63) x (head 0..7)
        int ln = id >> 3, hd = id & 7;
        int gn = blockIdx.x * 64 + ln;
        if (gn >= N) continue;
        const float* hp = &hL[ln * 65 + hd * 8];
        float as = 0.f, ad = 0.f;
        float hv[8];
        #pragma unroll
        for (int j = 0; j < 8; ++j) {
            hv[j] = hp[j];
            as += hv[j] * a_src[hd * 8 + j];
            ad += hv[j] * a_dst[hd * 8 + j];
        }
        adb[gn * 8 + hd] = ad * LOG2E;
        asb[gn * 8 + hd] = as * LOG2E;
        unsigned short u[8];
        #pragma unroll
        for (int j = 0; j < 8; ++j) u[j] = f2bf(hv[j]);
        uint4 pk;
        pk.x = (unsigned)u[0] | ((unsigned)u[1] << 16);
        pk.y = (unsigned)u[2] | ((unsigned)u[3] << 16);
        pk.z = (unsigned)u[4] | ((unsigned)u[5] << 16);
        pk.w = (unsigned)u[6] | ((unsigned)u[7] << 16);
        *(uint4*)(hrec + (size_t)gn * 128 + hd * 16) = pk;
    }
}

// ====== fused MFMA GEMM + pack40 (layer 2, COUT=40) -> 80 B records ======

__global__ __launch_bounds__(256) void gemm_pack40_k(
    const float* __restrict__ x, const float* __restrict__ W,
    const float* __restrict__ a_src, const float* __restrict__ a_dst,
    char* __restrict__ h40, float* __restrict__ asb40,
    float* __restrict__ adb, int N) {
    constexpr int K = 64, NT = 3, KT = 2;
    constexpr size_t WF_BYTES = (size_t)KT * NT * 64 * 8 * sizeof(short);
    constexpr size_t H_BYTES = (size_t)64 * 41 * sizeof(float);
    __shared__ alignas(16) char smem[WF_BYTES > H_BYTES ? WF_BYTES : H_BYTES];
    short* Wf = (short*)smem;
    float* hL = (float*)smem;
    int tid = threadIdx.x;
    for (int f = tid; f < KT * NT * 64; f += 256) {
        int lane = f & 63;
        int ntk = f >> 6;
        int nt = ntk % NT, kt = ntk / NT;
        int q = lane >> 4, c = lane & 15;
        int n = nt * 16 + c;
        int k0 = kt * 32 + q * 8;
        short8 frag;
        #pragma unroll
        for (int j = 0; j < 8; ++j) {
            float v = (n < 40) ? W[(size_t)(k0 + j) * 40 + n] : 0.f;
            frag[j] = (short)f2bf(v);
        }
        *(short8*)&Wf[f * 8] = frag;
    }
    __syncthreads();
    int wave = tid >> 6, lane = tid & 63;
    int q = lane >> 4, c = lane & 15;
    int m0 = blockIdx.x * 64 + wave * 16;
    int arow = m0 + c;
    int arl = arow < N ? arow : N - 1;
    f32x4 acc[NT] = {};
    for (int kt = 0; kt < KT; ++kt) {
        const float* xp = x + (size_t)arl * K + kt * 32 + q * 8;
        float4 a0 = *(const float4*)xp;
        float4 a1 = *(const float4*)(xp + 4);
        float av[8] = {a0.x, a0.y, a0.z, a0.w, a1.x, a1.y, a1.z, a1.w};
        short8 af;
        #pragma unroll
        for (int j = 0; j < 8; ++j) af[j] = (short)f2bf(av[j]);
        #pragma unroll
        for (int nt = 0; nt < NT; ++nt) {
            short8 bf = *(const short8*)&Wf[((kt * NT + nt) * 64 + lane) * 8];
            acc[nt] = __builtin_amdgcn_mfma_f32_16x16x32_bf16(af, bf, acc[nt],
                                                              0, 0, 0);
        }
    }
    __syncthreads();
    int lrow = wave * 16 + q * 4;
    #pragma unroll
    for (int nt = 0; nt < NT; ++nt) {
        int n = nt * 16 + c;
        if (n >= 40) continue;
        #pragma unroll
        for (int reg = 0; reg < 4; ++reg)
            hL[(lrow + reg) * 41 + n] = acc[nt][reg];
    }
    __syncthreads();
    // 4 threads per node compute pas/pad
    int ln = tid >> 2, sub = tid & 3;
    int gn = blockIdx.x * 64 + ln;
    float pas = 0.f, pad = 0.f;
    if (gn < N) {
        for (int j = sub; j < 40; j += 4) {
            float hv = hL[ln * 41 + j];
            pas += hv * a_src[j];
            pad += hv * a_dst[j];
        }
    }
    pas += __shfl_xor(pas, 1); pas += __shfl_xor(pas, 2);
    pad += __shfl_xor(pad, 1); pad += __shfl_xor(pad, 2);
    if (gn < N && sub == 0) {
        asb40[gn] = pas * LOG2E;
        adb[gn] = pad * LOG2E;
    }
    // write bf16 h, stride 80 B
    for (int i = tid; i < 64 * 40; i += 256) {
        int n2 = i / 40, ch = i % 40;
        int g2 = blockIdx.x * 64 + n2;
        if (g2 < N)
            *(unsigned short*)(h40 + (size_t)g2 * 80 + ch * 2) =
                f2bf(hL[n2 * 41 + ch]);
    }
}

// ======= aggr64: parallel weight phase + LDS broadcast, 16-deep unroll ======

#define EDGE64(SUF, IDX)                                                     \
    int s##SUF = __builtin_amdgcn_readlane(sv, (IDX));                       \
    float w##SUF = lwp[(IDX)];                                               \
    unsigned u##SUF =                                                        \
        *(const unsigned short*)(hrec + (size_t)s##SUF * 128 + lane2);

__global__ __launch_bounds__(256) void aggr64_k(
    const char* __restrict__ hrec, const float* __restrict__ asb,
    const float* __restrict__ adb, const int* __restrict__ row_ptr,
    const int* __restrict__ csr_src, const float* __restrict__ bias,
    float* __restrict__ out, int N) {
    __shared__ float wlds[4 * 1040];  // 4 waves x 2 buffers x (8*65)
    int wave = threadIdx.x >> 6;
    int node = blockIdx.x * 4 + wave;
    if (node >= N) return;
    int lane = threadIdx.x & 63;
    int hd = lane >> 3;
    int lane2 = lane * 2;
    float* wbA = wlds + wave * 1040;
    float* wbB = wbA + 520;
    const float* lwpA = wbA + hd * 65;
    const float* lwpB = wbB + hd * 65;
    int beg = row_ptr[node], end = row_ptr[node + 1];
    float4 adv0 = *(const float4*)(adb + (size_t)node * 8);
    float4 adv1 = *(const float4*)(adb + (size_t)node * 8 + 4);
    float acc0 = 0.f, acc1 = 0.f, acc2 = 0.f, acc3 = 0.f;
    float acc4 = 0.f, acc5 = 0.f, acc6 = 0.f, acc7 = 0.f;
    float l0 = 0.f, l1 = 0.f, l2 = 0.f, l3 = 0.f;
    float l4 = 0.f, l5 = 0.f, l6 = 0.f, l7 = 0.f;
    int par = 0;
    for (int i0 = beg; i0 < end; i0 += 64, par ^= 1) {
        int tail = end - i0;
        int sv = csr_src[i0 + (lane < tail ? lane : 0)];
        int cnt = tail < 64 ? tail : 64;
        float* wb = par ? wbB : wbA;
        const float* lwp = par ? lwpB : lwpA;
        // ---- parallel weight phase: this lane's edge, all 8 heads ----
        {
            const float* asp = asb + (size_t)sv * 8;
            float4 s0 = *(const float4*)asp;
            float4 s1 = *(const float4*)(asp + 4);
            float w0 = s0.x + adv0.x; w0 = fmaxf(w0, NEG_SLOPE * w0); w0 = fexp2(w0);
            float w1 = s0.y + adv0.y; w1 = fmaxf(w1, NEG_SLOPE * w1); w1 = fexp2(w1);
            float w2 = s0.z + adv0.z; w2 = fmaxf(w2, NEG_SLOPE * w2); w2 = fexp2(w2);
            float w3 = s0.w + adv0.w; w3 = fmaxf(w3, NEG_SLOPE * w3); w3 = fexp2(w3);
            float w4 = s1.x + adv1.x; w4 = fmaxf(w4, NEG_SLOPE * w4); w4 = fexp2(w4);
            float w5 = s1.y + adv1.y; w5 = fmaxf(w5, NEG_SLOPE * w5); w5 = fexp2(w5);
            float w6 = s1.z + adv1.z; w6 = fmaxf(w6, NEG_SLOPE * w6); w6 = fexp2(w6);
            float w7 = s1.w + adv1.w; w7 = fmaxf(w7, NEG_SLOPE * w7); w7 = fexp2(w7);
            wb[lane]       = w0;
            wb[65 + lane]  = w1;
            wb[130 + lane] = w2;
            wb[195 + lane] = w3;
            wb[260 + lane] = w4;
            wb[325 + lane] = w5;
            wb[390 + lane] = w6;
            wb[455 + lane] = w7;
        }
        // ---- fma phase: w via LDS broadcast, u via readlane'd base ----
        int j = 0;
        for (; j + 16 <= cnt; j += 16) {
            EDGE64(V0, j)       EDGE64(V1, j + 1)  EDGE64(V2, j + 2)  EDGE64(V3, j + 3)
            EDGE64(V4, j + 4)   EDGE64(V5, j + 5)  EDGE64(V6, j + 6)  EDGE64(V7, j + 7)
            EDGE64(V8, j + 8)   EDGE64(V9, j + 9)  EDGE64(V10, j + 10) EDGE64(V11, j + 11)
            EDGE64(V12, j + 12) EDGE64(V13, j + 13) EDGE64(V14, j + 14) EDGE64(V15, j + 15)
            l0 += wV0; l1 += wV1; l2 += wV2; l3 += wV3;
            l4 += wV4; l5 += wV5; l6 += wV6; l7 += wV7;
            l0 += wV8; l1 += wV9; l2 += wV10; l3 += wV11;
            l4 += wV12; l5 += wV13; l6 += wV14; l7 += wV15;
            acc0 = fmaf(wV0, __uint_as_float(uV0 << 16), acc0);
            acc1 = fmaf(wV1, __uint_as_float(uV1 << 16), acc1);
            acc2 = fmaf(wV2, __uint_as_float(uV2 << 16), acc2);
            acc3 = fmaf(wV3, __uint_as_float(uV3 << 16), acc3);
            acc4 = fmaf(wV4, __uint_as_float(uV4 << 16), acc4);
            acc5 = fmaf(wV5, __uint_as_float(uV5 << 16), acc5);
            acc6 = fmaf(wV6, __uint_as_float(uV6 << 16), acc6);
            acc7 = fmaf(wV7, __uint_as_float(uV7 << 16), acc7);
            acc0 = fmaf(wV8, __uint_as_float(uV8 << 16), acc0);
            acc1 = fmaf(wV9, __uint_as_float(uV9 << 16), acc1);
            acc2 = fmaf(wV10, __uint_as_float(uV10 << 16), acc2);
            acc3 = fmaf(wV11, __uint_as_float(uV11 << 16), acc3);
            acc4 = fmaf(wV12, __uint_as_float(uV12 << 16), acc4);
            acc5 = fmaf(wV13, __uint_as_float(uV13 << 16), acc5);
            acc6 = fmaf(wV14, __uint_as_float(uV14 << 16), acc6);
            acc7 = fmaf(wV15, __uint_as_float(uV15 << 16), acc7);
        }
        for (; j + 4 <= cnt; j += 4) {
            EDGE64(A, j) EDGE64(B, j + 1) EDGE64(C, j + 2) EDGE64(D, j + 3)
            l0 += wA; l1 += wB; l2 += wC; l3 += wD;
            acc0 = fmaf(wA, __uint_as_float(uA << 16), acc0);
            acc1 = fmaf(wB, __uint_as_float(uB << 16), acc1);
            acc2 = fmaf(wC, __uint_as_float(uC << 16), acc2);
            acc3 = fmaf(wD, __uint_as_float(uD << 16), acc3);
        }
        for (; j < cnt; ++j) {
            EDGE64(A, j)
            l0 += wA;
            acc0 = fmaf(wA, __uint_as_float(uA << 16), acc0);
        }
    }
    float l = ((l0 + l1) + (l2 + l3)) + ((l4 + l5) + (l6 + l7));
    float acc = ((acc0 + acc1) + (acc2 + acc3)) + ((acc4 + acc5) + (acc6 + acc7));
    out[(size_t)node * 64 + lane] = acc / (l + 1e-16f) + bias[lane];
}

// ======= aggr40: parallel weight phase + readlane fma, 16-deep unroll =======

#define F40(SUF, IDX)                                                        \
    int s##SUF = __builtin_amdgcn_readlane(sv, (IDX));                       \
    float w##SUF = readlane_f(wv, (IDX));                                    \
    unsigned u##SUF =                                                        \
        *(const unsigned short*)(hrec + (size_t)s##SUF * 80 + cl2);

__global__ __launch_bounds__(256) void aggr40_k(
    const char* __restrict__ hrec, const float* __restrict__ asb,
    const float* __restrict__ adb, const int* __restrict__ row_ptr,
    const int* __restrict__ csr_src, const float* __restrict__ bias,
    float* __restrict__ out, int N) {
    int node = blockIdx.x * 4 + (threadIdx.x >> 6);
    if (node >= N) return;
    int lane = threadIdx.x & 63;
    int cl2 = (lane < 40 ? lane : 0) * 2;
    int beg = row_ptr[node], end = row_ptr[node + 1];
    float ad = adb[node];
    float acc0 = 0.f, acc1 = 0.f, acc2 = 0.f, acc3 = 0.f;
    float acc4 = 0.f, acc5 = 0.f, acc6 = 0.f, acc7 = 0.f;
    float lpart = 0.f;
    for (int i0 = beg; i0 < end; i0 += 64) {
        int tail = end - i0;
        int sv = csr_src[i0 + (lane < tail ? lane : 0)];
        int cnt = tail < 64 ? tail : 64;
        // ---- parallel weight phase: lane computes its own edge's weight ----
        float as = asb[sv];
        float v = as + ad;
        v = fmaxf(v, NEG_SLOPE * v);
        float wv = fexp2(v);
        wv = (lane < cnt) ? wv : 0.f;
        lpart += wv;
        // ---- fma phase: branch-free, weights via readlane ----
        int j = 0;
        for (; j + 16 <= cnt; j += 16) {
            F40(V0, j)       F40(V1, j + 1)  F40(V2, j + 2)  F40(V3, j + 3)
            F40(V4, j + 4)   F40(V5, j + 5)  F40(V6, j + 6)  F40(V7, j + 7)
            F40(V8, j + 8)   F40(V9, j + 9)  F40(V10, j + 10) F40(V11, j + 11)
            F40(V12, j + 12) F40(V13, j + 13) F40(V14, j + 14) F40(V15, j + 15)
            acc0 = fmaf(wV0, __uint_as_float(uV0 << 16), acc0);
            acc1 = fmaf(wV1, __uint_as_float(uV1 << 16), acc1);
            acc2 = fmaf(wV2, __uint_as_float(uV2 << 16), acc2);
            acc3 = fmaf(wV3, __uint_as_float(uV3 << 16), acc3);
            acc4 = fmaf(wV4, __uint_as_float(uV4 << 16), acc4);
            acc5 = fmaf(wV5, __uint_as_float(uV5 << 16), acc5);
            acc6 = fmaf(wV6, __uint_as_float(uV6 << 16), acc6);
            acc7 = fmaf(wV7, __uint_as_float(uV7 << 16), acc7);
            acc0 = fmaf(wV8, __uint_as_float(uV8 << 16), acc0);
            acc1 = fmaf(wV9, __uint_as_float(uV9 << 16), acc1);
            acc2 = fmaf(wV10, __uint_as_float(uV10 << 16), acc2);
            acc3 = fmaf(wV11, __uint_as_float(uV11 << 16), acc3);
            acc4 = fmaf(wV12, __uint_as_float(uV12 << 16), acc4);
            acc5 = fmaf(wV13, __uint_as_float(uV13 << 16), acc5);
            acc6 = fmaf(wV14, __uint_as_float(uV14 << 16), acc6);
            acc7 = fmaf(wV15, __uint_as_float(uV15 << 16), acc7);
        }
        for (; j + 4 <= cnt; j += 4) {
            F40(A, j) F40(B, j + 1) F40(C, j + 2) F40(D, j + 3)
            acc0 = fmaf(wA, __uint_as_float(uA << 16), acc0);
            acc1 = fmaf(wB, __uint_as_float(uB << 16), acc1);
            acc2 = fmaf(wC, __uint_as_float(uC << 16), acc2);
            acc3 = fmaf(wD, __uint_as_float(uD << 16), acc3);
        }
        for (; j < cnt; ++j) {
            F40(A, j)
            acc0 = fmaf(wA, __uint_as_float(uA << 16), acc0);
        }
    }
    // reduce l across all lanes (each lane holds partial sum of its edges)
    #pragma unroll
    for (int off = 32; off > 0; off >>= 1) lpart += __shfl_xor(lpart, off);
    float l = lpart;
    float acc = ((acc0 + acc1) + (acc2 + acc3)) + ((acc4 + acc5) + (acc6 + acc7));
    // fused bias + log_softmax over the 40 class lanes
    float val = acc / (l + 1e-16f) + ((lane < 40) ? bias[lane] : 0.f);
    float mval = (lane < 40) ? val : -1e30f;
    #pragma unroll
    for (int off = 32; off > 0; off >>= 1)
        mval = fmaxf(mval, __shfl_xor(mval, off));
    float ex = (lane < 40) ? __expf(val - mval) : 0.f;
    #pragma unroll
    for (int off = 32; off > 0; off >>= 1) ex += __shfl_xor(ex, off);
    if (lane < 40)
        out[(size_t)node * 40 + lane] = val - mval - __logf(ex);
}

// =================== launch ===================

extern "C" void kernel_launch(void* const* d_in, const int* in_sizes, int n_in,
                              void* d_out, int out_size, void* d_ws,
                              size_t ws_size, hipStream_t stream) {
    const float* features = (const float*)d_in[0];
    const int* edge_index = (const int*)d_in[1];
    const float* W0 = (const float*)d_in[2];
    const float* as0 = (const float*)d_in[3];
    const float* ad0 = (const float*)d_in[4];
    const float* b0 = (const float*)d_in[5];
    const float* W1 = (const float*)d_in[6];
    const float* as1 = (const float*)d_in[7];
    const float* ad1 = (const float*)d_in[8];
    const float* b1 = (const float*)d_in[9];
    const float* W2 = (const float*)d_in[10];
    const float* as2 = (const float*)d_in[11];
    const float* ad2 = (const float*)d_in[12];
    const float* b2 = (const float*)d_in[13];

    int N = in_sizes[0] / 256;
    int E = in_sizes[1] / 2;
    int Etot = E + N;
    int NB = (N + 255) >> 8;       // 256-node blocks for scan (<= 512)
    int nbuck = (N + 63) >> 6;     // 64-node buckets (<= MAXBUCK)
    const int* srcs = edge_index;
    const int* dsts = edge_index + E;

    // workspace layout
    float* ws = (float*)d_ws;
    float* Hbuf = ws;                              // N*64 floats (pairs scratch)
    float* Abuf = Hbuf + (size_t)N * 64;           // N*64 floats
    float* adb  = Abuf + (size_t)N * 64;           // N*8
    float* asb  = adb + (size_t)N * 8;             // N*8
    char* hrec  = (char*)(asb + (size_t)N * 8);    // N*128 bytes
    int* row_ptr = (int*)(hrec + (size_t)N * 128); // N+1
    int* deg     = row_ptr + (N + 2);              // N
    int* bsum    = deg + N;                        // 512
    int* bbase   = bsum + 512;                     // 512
    int* bptrE   = bbase + 512;                    // nbuck
    int* bcurE   = bptrE + nbuck;                  // nbuck
    int* csr_src = bcurE + nbuck;                  // Etot
    int* pairs   = (int*)Hbuf;                     // scratch, dead before gemm

    const int B = 256;
    int gAg = (N + 3) / 4;
    int gGm = (N + 63) / 64;
    int nq = (E + 3) >> 2;
    int gEd = (nq + 255) / 256;
    if (gEd > 8192) gEd = 8192;
    int gBp = (nbuck + 255) / 256;
    int gSc = (E + EPB - 1) / EPB;

    // ---------- CSR build ----------
    (void)hipMemsetAsync(deg, 0, (size_t)N * 4, stream);
    deg_count_k<<<gEd, B, 0, stream>>>(dsts, deg, E);
    scan_part_k<<<NB, B, 0, stream>>>(deg, bsum, N);
    scan_top_k<<<1, 512, 0, stream>>>(bsum, bbase, row_ptr, NB, N, Etot);
    scan_write_k<<<NB, B, 0, stream>>>(deg, bbase, row_ptr, csr_src, N);
    bptr_init_k<<<gBp, B, 0, stream>>>(row_ptr, bptrE, bcurE, nbuck);
    bscatter_k<<<gSc, B, 0, stream>>>(srcs, dsts, bcurE, pairs, E, nbuck);
    bucket_sort_k<<<nbuck, B, 0, stream>>>(pairs, bptrE, bcurE, row_ptr,
                                           csr_src, N);

    // ---------------- layer 0 ----------------
    gemm_pack8_k<256><<<gGm, B, 0, stream>>>(features, W0, as0, ad0, hrec,
                                             asb, adb, N);
    aggr64_k<<<gAg, B, 0, stream>>>(hrec, asb, adb, row_ptr, csr_src, b0,
                                    Abuf, N);

    // ---------------- layer 1 ----------------
    gemm_pack8_k<64><<<gGm, B, 0, stream>>>(Abuf, W1, as1, ad1, hrec, asb,
                                            adb, N);
    aggr64_k<<<gAg, B, 0, stream>>>(hrec, asb, adb, row_ptr, csr_src, b1,
                                    Abuf, N);

    // ---------------- layer 2 ----------------
    gemm_pack40_k<<<gGm, B, 0, stream>>>(Abuf, W2, as2, ad2, hrec, asb, adb,
                                         N);
    aggr40_k<<<gAg, B, 0, stream>>>(hrec, asb, adb, row_ptr, csr_src, b2,
                                    (float*)d_out, N);
}

// Round 5
// 579.596 us; speedup vs baseline: 1.9166x; 1.3229x over previous
//
#include <hip/hip_runtime.h>
#include <hip/hip_bf16.h>

#define NEG_SLOPE 0.2f
#define LOG2E 1.44269504f
#define EPB 8192      // edges per hist/scatter block
#define MAXBUCK 800   // >= ceil(N/128)

typedef __attribute__((ext_vector_type(8))) short short8;
typedef __attribute__((ext_vector_type(4))) float f32x4;

__device__ __forceinline__ unsigned short f2bf(float x) {
    unsigned u = __float_as_uint(x);
    unsigned r = (u + 0x7FFFu + ((u >> 16) & 1u)) >> 16;  // RNE
    return (unsigned short)r;
}

__device__ __forceinline__ float fexp2(float x) {
    return __builtin_amdgcn_exp2f(x);  // v_exp_f32: 2^x
}

__device__ __forceinline__ float readlane_f(float v, int l) {
    return __int_as_float(__builtin_amdgcn_readlane(__float_as_int(v), l));
}

// ===== CSR build: bucket(128-node) hist -> scan -> scatter -> LDS sort =====
// No per-node global atomics anywhere: all global atomic frontiers are
// bucket-level (nbuck<=800 counters, ~50 lines).

__global__ __launch_bounds__(256) void bucket_hist_k(
    const int* __restrict__ dsts, int* __restrict__ bcnt,
    int* __restrict__ bhist, int E, int nbuck) {
    __shared__ int lh[MAXBUCK];
    int t = threadIdx.x;
    for (int i = t; i < nbuck; i += 256) lh[i] = 0;
    __syncthreads();
    int base = blockIdx.x * EPB;
    int cnt = E - base;
    if (cnt > EPB) cnt = EPB;
    int nq = cnt >> 2;
    const int4* d4p = (const int4*)(dsts + base);
    for (int i = t; i < nq; i += 256) {
        int4 d = d4p[i];
        atomicAdd(&lh[d.x >> 7], 1);
        atomicAdd(&lh[d.y >> 7], 1);
        atomicAdd(&lh[d.z >> 7], 1);
        atomicAdd(&lh[d.w >> 7], 1);
    }
    for (int i = (nq << 2) + t; i < cnt; i += 256)
        atomicAdd(&lh[dsts[base + i] >> 7], 1);
    __syncthreads();
    int* bh = bhist + (size_t)blockIdx.x * MAXBUCK;
    for (int i = t; i < nbuck; i += 256) {
        int c = lh[i];
        bh[i] = c;
        if (c) atomicAdd(&bcnt[i], c);
    }
}

// 1-block exclusive scan of bucket counts (nbuck <= 2048)
__global__ __launch_bounds__(512) void bucket_scan_k(
    const int* __restrict__ bcnt, int* __restrict__ bptrE,
    int* __restrict__ bcurE, int nbuck) {
    __shared__ int csum[512];
    int t = threadIdx.x;
    int i0 = t * 4;
    int v0 = 0, v1 = 0, v2 = 0, v3 = 0;
    if (i0 < nbuck) v0 = bcnt[i0];
    if (i0 + 1 < nbuck) v1 = bcnt[i0 + 1];
    if (i0 + 2 < nbuck) v2 = bcnt[i0 + 2];
    if (i0 + 3 < nbuck) v3 = bcnt[i0 + 3];
    int s = v0 + v1 + v2 + v3;
    csum[t] = s;
    __syncthreads();
    for (int off = 1; off < 512; off <<= 1) {
        int x = (t >= off) ? csum[t - off] : 0;
        __syncthreads();
        csum[t] += x;
        __syncthreads();
    }
    int base = csum[t] - s;
    if (i0 < nbuck)     { bptrE[i0] = base;     bcurE[i0] = base; }     base += v0;
    if (i0 + 1 < nbuck) { bptrE[i0 + 1] = base; bcurE[i0 + 1] = base; } base += v1;
    if (i0 + 2 < nbuck) { bptrE[i0 + 2] = base; bcurE[i0 + 2] = base; } base += v2;
    if (i0 + 3 < nbuck) { bptrE[i0 + 3] = base; bcurE[i0 + 3] = base; }
}

// packed scatter into bucket segments; per-block hist comes from bhist
__global__ __launch_bounds__(256) void bscatter_k(
    const int* __restrict__ srcs, const int* __restrict__ dsts,
    const int* __restrict__ bhist, int* __restrict__ bcurE,
    int* __restrict__ pairs, int E, int nbuck) {
    __shared__ int lh[MAXBUCK];
    __shared__ int lbase[MAXBUCK];
    int t = threadIdx.x;
    const int* bh = bhist + (size_t)blockIdx.x * MAXBUCK;
    for (int i = t; i < nbuck; i += 256) {
        int c = bh[i];
        lbase[i] = c ? atomicAdd(&bcurE[i], c) : 0;
        lh[i] = 0;
    }
    __syncthreads();
    int base = blockIdx.x * EPB;
    int cnt = E - base;
    if (cnt > EPB) cnt = EPB;
    int nq = cnt >> 2;
    const int4* d4p = (const int4*)(dsts + base);
    const int4* s4p = (const int4*)(srcs + base);
    for (int i = t; i < nq; i += 256) {
        int4 d = d4p[i];
        int4 s = s4p[i];
        int b0 = d.x >> 7, b1 = d.y >> 7, b2 = d.z >> 7, b3 = d.w >> 7;
        int r0 = atomicAdd(&lh[b0], 1);
        int r1 = atomicAdd(&lh[b1], 1);
        int r2 = atomicAdd(&lh[b2], 1);
        int r3 = atomicAdd(&lh[b3], 1);
        pairs[lbase[b0] + r0] = (s.x << 7) | (d.x & 127);
        pairs[lbase[b1] + r1] = (s.y << 7) | (d.y & 127);
        pairs[lbase[b2] + r2] = (s.z << 7) | (d.z & 127);
        pairs[lbase[b3] + r3] = (s.w << 7) | (d.w & 127);
    }
    for (int i = (nq << 2) + t; i < cnt; i += 256) {
        int s = srcs[base + i], d = dsts[base + i];
        int r = atomicAdd(&lh[d >> 7], 1);
        pairs[lbase[d >> 7] + r] = (s << 7) | (d & 127);
    }
}

// per-bucket: LDS hist(128) + scan -> row_ptr + self-loop + sorted csr_src
__global__ __launch_bounds__(256) void bucket_sort_k(
    const int* __restrict__ pairs, const int* __restrict__ bptrE,
    const int* __restrict__ bcurE, int* __restrict__ row_ptr,
    int* __restrict__ csr_src, int N, int Etot) {
    __shared__ int lh[128];
    __shared__ int sc[128];
    int b = blockIdx.x;
    int n0 = b << 7;
    int t = threadIdx.x;
    if (t < 128) lh[t] = 0;
    __syncthreads();
    int e0 = bptrE[b], e1 = bcurE[b];
    for (int e = e0 + t; e < e1; e += 256)
        atomicAdd(&lh[pairs[e] & 127], 1);
    __syncthreads();
    if (t < 128) sc[t] = lh[t];
    __syncthreads();
    for (int off = 1; off < 128; off <<= 1) {
        int x = (t < 128 && t >= off) ? sc[t - off] : 0;
        __syncthreads();
        if (t < 128) sc[t] += x;
        __syncthreads();
    }
    if (t < 128) {
        int cntv = lh[t];
        int excl = sc[t] - cntv;
        int n = n0 + t;
        int rp = e0 + n0 + t + excl;  // edges before n + self-loops before n
        if (n < N) {
            row_ptr[n] = rp;
            csr_src[rp] = n;  // self-loop at slot 0
        }
        lh[t] = rp + 1;  // cursor
    }
    __syncthreads();
    for (int e = e0 + t; e < e1; e += 256) {
        int p = pairs[e];
        int pos = atomicAdd(&lh[p & 127], 1);
        csr_src[pos] = p >> 7;
    }
    if (b == 0 && t == 0) row_ptr[N] = Etot;
}

// ====== fused MFMA GEMM + pack (COUT=64): x[N,K] @ W[K,64] -> hrec/asb/adb ==

template <int K>
__global__ __launch_bounds__(256) void gemm_pack8_k(
    const float* __restrict__ x, const float* __restrict__ W,
    const float* __restrict__ a_src, const float* __restrict__ a_dst,
    char* __restrict__ hrec, float* __restrict__ asb,
    float* __restrict__ adb, int N) {
    constexpr int NT = 4;
    constexpr int KT = K / 32;
    constexpr size_t WF_BYTES = (size_t)KT * NT * 64 * 8 * sizeof(short);
    constexpr size_t H_BYTES = (size_t)64 * 65 * sizeof(float);
    __shared__ alignas(16) char smem[WF_BYTES > H_BYTES ? WF_BYTES : H_BYTES];
    short* Wf = (short*)smem;
    float* hL = (float*)smem;
    int tid = threadIdx.x;
    for (int f = tid; f < KT * NT * 64; f += 256) {
        int lane = f & 63;
        int ntk = f >> 6;
        int nt = ntk % NT, kt = ntk / NT;
        int q = lane >> 4, c = lane & 15;
        int n = nt * 16 + c;
        int k0 = kt * 32 + q * 8;
        short8 frag;
        #pragma unroll
        for (int j = 0; j < 8; ++j)
            frag[j] = (short)f2bf(W[(size_t)(k0 + j) * 64 + n]);
        *(short8*)&Wf[f * 8] = frag;
    }
    __syncthreads();
    int wave = tid >> 6, lane = tid & 63;
    int q = lane >> 4, c = lane & 15;
    int m0 = blockIdx.x * 64 + wave * 16;
    int arow = m0 + c;
    int arl = arow < N ? arow : N - 1;
    f32x4 acc[NT] = {};
    for (int kt = 0; kt < KT; ++kt) {
        const float* xp = x + (size_t)arl * K + kt * 32 + q * 8;
        float4 a0 = *(const float4*)xp;
        float4 a1 = *(const float4*)(xp + 4);
        float av[8] = {a0.x, a0.y, a0.z, a0.w, a1.x, a1.y, a1.z, a1.w};
        short8 af;
        #pragma unroll
        for (int j = 0; j < 8; ++j) af[j] = (short)f2bf(av[j]);
        #pragma unroll
        for (int nt = 0; nt < NT; ++nt) {
            short8 bf = *(const short8*)&Wf[((kt * NT + nt) * 64 + lane) * 8];
            acc[nt] = __builtin_amdgcn_mfma_f32_16x16x32_bf16(af, bf, acc[nt],
                                                              0, 0, 0);
        }
    }
    __syncthreads();  // all waves done reading Wf; reuse as hL
    int lrow = wave * 16 + q * 4;
    #pragma unroll
    for (int nt = 0; nt < NT; ++nt)
        #pragma unroll
        for (int reg = 0; reg < 4; ++reg)
            hL[(lrow + reg) * 65 + nt * 16 + c] = acc[nt][reg];
    __syncthreads();
    #pragma unroll
    for (int it = 0; it < 2; ++it) {
        int id = it * 256 + tid;  // 0..511 = (node 0..63) x (head 0..7)
        int ln = id >> 3, hd = id & 7;
        int gn = blockIdx.x * 64 + ln;
        if (gn >= N) continue;
        const float* hp = &hL[ln * 65 + hd * 8];
        float as = 0.f, ad = 0.f;
        float hv[8];
        #pragma unroll
        for (int j = 0; j < 8; ++j) {
            hv[j] = hp[j];
            as += hv[j] * a_src[hd * 8 + j];
            ad += hv[j] * a_dst[hd * 8 + j];
        }
        adb[gn * 8 + hd] = ad * LOG2E;
        asb[gn * 8 + hd] = as * LOG2E;
        unsigned short u[8];
        #pragma unroll
        for (int j = 0; j < 8; ++j) u[j] = f2bf(hv[j]);
        uint4 pk;
        pk.x = (unsigned)u[0] | ((unsigned)u[1] << 16);
        pk.y = (unsigned)u[2] | ((unsigned)u[3] << 16);
        pk.z = (unsigned)u[4] | ((unsigned)u[5] << 16);
        pk.w = (unsigned)u[6] | ((unsigned)u[7] << 16);
        *(uint4*)(hrec + (size_t)gn * 128 + hd * 16) = pk;
    }
}

// ====== fused MFMA GEMM + pack40 (layer 2, COUT=40) -> 80 B records ======

__global__ __launch_bounds__(256) void gemm_pack40_k(
    const float* __restrict__ x, const float* __restrict__ W,
    const float* __restrict__ a_src, const float* __restrict__ a_dst,
    char* __restrict__ h40, float* __restrict__ asb40,
    float* __restrict__ adb, int N) {
    constexpr int K = 64, NT = 3, KT = 2;
    constexpr size_t WF_BYTES = (size_t)KT * NT * 64 * 8 * sizeof(short);
    constexpr size_t H_BYTES = (size_t)64 * 41 * sizeof(float);
    __shared__ alignas(16) char smem[WF_BYTES > H_BYTES ? WF_BYTES : H_BYTES];
    short* Wf = (short*)smem;
    float* hL = (float*)smem;
    int tid = threadIdx.x;
    for (int f = tid; f < KT * NT * 64; f += 256) {
        int lane = f & 63;
        int ntk = f >> 6;
        int nt = ntk % NT, kt = ntk / NT;
        int q = lane >> 4, c = lane & 15;
        int n = nt * 16 + c;
        int k0 = kt * 32 + q * 8;
        short8 frag;
        #pragma unroll
        for (int j = 0; j < 8; ++j) {
            float v = (n < 40) ? W[(size_t)(k0 + j) * 40 + n] : 0.f;
            frag[j] = (short)f2bf(v);
        }
        *(short8*)&Wf[f * 8] = frag;
    }
    __syncthreads();
    int wave = tid >> 6, lane = tid & 63;
    int q = lane >> 4, c = lane & 15;
    int m0 = blockIdx.x * 64 + wave * 16;
    int arow = m0 + c;
    int arl = arow < N ? arow : N - 1;
    f32x4 acc[NT] = {};
    for (int kt = 0; kt < KT; ++kt) {
        const float* xp = x + (size_t)arl * K + kt * 32 + q * 8;
        float4 a0 = *(const float4*)xp;
        float4 a1 = *(const float4*)(xp + 4);
        float av[8] = {a0.x, a0.y, a0.z, a0.w, a1.x, a1.y, a1.z, a1.w};
        short8 af;
        #pragma unroll
        for (int j = 0; j < 8; ++j) af[j] = (short)f2bf(av[j]);
        #pragma unroll
        for (int nt = 0; nt < NT; ++nt) {
            short8 bf = *(const short8*)&Wf[((kt * NT + nt) * 64 + lane) * 8];
            acc[nt] = __builtin_amdgcn_mfma_f32_16x16x32_bf16(af, bf, acc[nt],
                                                              0, 0, 0);
        }
    }
    __syncthreads();
    int lrow = wave * 16 + q * 4;
    #pragma unroll
    for (int nt = 0; nt < NT; ++nt) {
        int n = nt * 16 + c;
        if (n >= 40) continue;
        #pragma unroll
        for (int reg = 0; reg < 4; ++reg)
            hL[(lrow + reg) * 41 + n] = acc[nt][reg];
    }
    __syncthreads();
    // 4 threads per node compute pas/pad
    int ln = tid >> 2, sub = tid & 3;
    int gn = blockIdx.x * 64 + ln;
    float pas = 0.f, pad = 0.f;
    if (gn < N) {
        for (int j = sub; j < 40; j += 4) {
            float hv = hL[ln * 41 + j];
            pas += hv * a_src[j];
            pad += hv * a_dst[j];
        }
    }
    pas += __shfl_xor(pas, 1); pas += __shfl_xor(pas, 2);
    pad += __shfl_xor(pad, 1); pad += __shfl_xor(pad, 2);
    if (gn < N && sub == 0) {
        asb40[gn] = pas * LOG2E;
        adb[gn] = pad * LOG2E;
    }
    // write bf16 h, stride 80 B
    for (int i = tid; i < 64 * 40; i += 256) {
        int n2 = i / 40, ch = i % 40;
        int g2 = blockIdx.x * 64 + n2;
        if (g2 < N)
            *(unsigned short*)(h40 + (size_t)g2 * 80 + ch * 2) =
                f2bf(hL[n2 * 41 + ch]);
    }
}

// ======= aggr64: parallel weight phase (8 exp / 64 edges) + LDS broadcast ===

#define EDGE64(SUF, IDX)                                                     \
    int s##SUF = __builtin_amdgcn_readlane(sv, (IDX));                       \
    float w##SUF = lwp[(IDX)];                                               \
    unsigned u##SUF =                                                        \
        *(const unsigned short*)(hrec + (size_t)s##SUF * 128 + lane2);

__global__ __launch_bounds__(256) void aggr64_k(
    const char* __restrict__ hrec, const float* __restrict__ asb,
    const float* __restrict__ adb, const int* __restrict__ row_ptr,
    const int* __restrict__ csr_src, const float* __restrict__ bias,
    float* __restrict__ out, int N) {
    __shared__ float wlds[4 * 1040];  // 4 waves x 2 buffers x (8*65)
    int wave = threadIdx.x >> 6;
    int node = blockIdx.x * 4 + wave;
    if (node >= N) return;
    int lane = threadIdx.x & 63;
    int hd = lane >> 3;
    int lane2 = lane * 2;
    float* wbA = wlds + wave * 1040;
    float* wbB = wbA + 520;
    const float* lwpA = wbA + hd * 65;
    const float* lwpB = wbB + hd * 65;
    int beg = row_ptr[node], end = row_ptr[node + 1];
    float4 adv0 = *(const float4*)(adb + (size_t)node * 8);
    float4 adv1 = *(const float4*)(adb + (size_t)node * 8 + 4);
    float acc0 = 0.f, acc1 = 0.f, acc2 = 0.f, acc3 = 0.f;
    float acc4 = 0.f, acc5 = 0.f, acc6 = 0.f, acc7 = 0.f;
    float l0 = 0.f, l1 = 0.f, l2 = 0.f, l3 = 0.f;
    float l4 = 0.f, l5 = 0.f, l6 = 0.f, l7 = 0.f;
    int par = 0;
    for (int i0 = beg; i0 < end; i0 += 64, par ^= 1) {
        int tail = end - i0;
        int sv = csr_src[i0 + (lane < tail ? lane : 0)];
        int cnt = tail < 64 ? tail : 64;
        float* wb = par ? wbB : wbA;
        const float* lwp = par ? lwpB : lwpA;
        // ---- parallel weight phase: this lane's edge, all 8 heads ----
        {
            const float* asp = asb + (size_t)sv * 8;
            float4 s0 = *(const float4*)asp;
            float4 s1 = *(const float4*)(asp + 4);
            float w0 = s0.x + adv0.x; w0 = fmaxf(w0, NEG_SLOPE * w0); w0 = fexp2(w0);
            float w1 = s0.y + adv0.y; w1 = fmaxf(w1, NEG_SLOPE * w1); w1 = fexp2(w1);
            float w2 = s0.z + adv0.z; w2 = fmaxf(w2, NEG_SLOPE * w2); w2 = fexp2(w2);
            float w3 = s0.w + adv0.w; w3 = fmaxf(w3, NEG_SLOPE * w3); w3 = fexp2(w3);
            float w4 = s1.x + adv1.x; w4 = fmaxf(w4, NEG_SLOPE * w4); w4 = fexp2(w4);
            float w5 = s1.y + adv1.y; w5 = fmaxf(w5, NEG_SLOPE * w5); w5 = fexp2(w5);
            float w6 = s1.z + adv1.z; w6 = fmaxf(w6, NEG_SLOPE * w6); w6 = fexp2(w6);
            float w7 = s1.w + adv1.w; w7 = fmaxf(w7, NEG_SLOPE * w7); w7 = fexp2(w7);
            wb[lane]       = w0;
            wb[65 + lane]  = w1;
            wb[130 + lane] = w2;
            wb[195 + lane] = w3;
            wb[260 + lane] = w4;
            wb[325 + lane] = w5;
            wb[390 + lane] = w6;
            wb[455 + lane] = w7;
        }
        // ---- fma phase: w via LDS broadcast, u via readlane'd base ----
        int j = 0;
        for (; j + 8 <= cnt; j += 8) {
            EDGE64(A, j)      EDGE64(B, j + 1) EDGE64(C, j + 2) EDGE64(D, j + 3)
            EDGE64(E2, j + 4) EDGE64(F, j + 5) EDGE64(G, j + 6) EDGE64(H2, j + 7)
            l0 += wA; l1 += wB; l2 += wC; l3 += wD;
            l4 += wE2; l5 += wF; l6 += wG; l7 += wH2;
            acc0 = fmaf(wA, __uint_as_float(uA << 16), acc0);
            acc1 = fmaf(wB, __uint_as_float(uB << 16), acc1);
            acc2 = fmaf(wC, __uint_as_float(uC << 16), acc2);
            acc3 = fmaf(wD, __uint_as_float(uD << 16), acc3);
            acc4 = fmaf(wE2, __uint_as_float(uE2 << 16), acc4);
            acc5 = fmaf(wF, __uint_as_float(uF << 16), acc5);
            acc6 = fmaf(wG, __uint_as_float(uG << 16), acc6);
            acc7 = fmaf(wH2, __uint_as_float(uH2 << 16), acc7);
        }
        for (; j + 4 <= cnt; j += 4) {
            EDGE64(A, j) EDGE64(B, j + 1) EDGE64(C, j + 2) EDGE64(D, j + 3)
            l0 += wA; l1 += wB; l2 += wC; l3 += wD;
            acc0 = fmaf(wA, __uint_as_float(uA << 16), acc0);
            acc1 = fmaf(wB, __uint_as_float(uB << 16), acc1);
            acc2 = fmaf(wC, __uint_as_float(uC << 16), acc2);
            acc3 = fmaf(wD, __uint_as_float(uD << 16), acc3);
        }
        for (; j < cnt; ++j) {
            EDGE64(A, j)
            l0 += wA;
            acc0 = fmaf(wA, __uint_as_float(uA << 16), acc0);
        }
    }
    float l = ((l0 + l1) + (l2 + l3)) + ((l4 + l5) + (l6 + l7));
    float acc = ((acc0 + acc1) + (acc2 + acc3)) + ((acc4 + acc5) + (acc6 + acc7));
    out[(size_t)node * 64 + lane] = acc / (l + 1e-16f) + bias[lane];
}

// ======= aggr40: parallel weight phase (1 exp / 64 edges) + readlane fma ====

#define F40(SUF, IDX)                                                        \
    int s##SUF = __builtin_amdgcn_readlane(sv, (IDX));                       \
    float w##SUF = readlane_f(wv, (IDX));                                    \
    unsigned u##SUF =                                                        \
        *(const unsigned short*)(rec40 + (size_t)s##SUF * 80 + cl2);

__global__ __launch_bounds__(256) void aggr40_k(
    const char* __restrict__ rec40, const float* __restrict__ asb,
    const float* __restrict__ adb, const int* __restrict__ row_ptr,
    const int* __restrict__ csr_src, const float* __restrict__ bias,
    float* __restrict__ out, int N) {
    int node = blockIdx.x * 4 + (threadIdx.x >> 6);
    if (node >= N) return;
    int lane = threadIdx.x & 63;
    int cl2 = (lane < 40 ? lane : 0) * 2;
    int beg = row_ptr[node], end = row_ptr[node + 1];
    float ad = adb[node];
    float acc0 = 0.f, acc1 = 0.f, acc2 = 0.f, acc3 = 0.f;
    float acc4 = 0.f, acc5 = 0.f, acc6 = 0.f, acc7 = 0.f;
    float lpart = 0.f;
    for (int i0 = beg; i0 < end; i0 += 64) {
        int tail = end - i0;
        int sv = csr_src[i0 + (lane < tail ? lane : 0)];
        int cnt = tail < 64 ? tail : 64;
        // ---- parallel weight phase: lane computes its own edge's weight ----
        float as = asb[sv];
        float v = as + ad;
        v = fmaxf(v, NEG_SLOPE * v);
        float wv = fexp2(v);
        wv = (lane < cnt) ? wv : 0.f;
        lpart += wv;
        // ---- fma phase: branch-free, weights via readlane ----
        int j = 0;
        for (; j + 8 <= cnt; j += 8) {
            F40(A, j)     F40(B, j + 1) F40(C, j + 2) F40(D, j + 3)
            F40(E2, j + 4) F40(F, j + 5) F40(G, j + 6) F40(H2, j + 7)
            acc0 = fmaf(wA, __uint_as_float(uA << 16), acc0);
            acc1 = fmaf(wB, __uint_as_float(uB << 16), acc1);
            acc2 = fmaf(wC, __uint_as_float(uC << 16), acc2);
            acc3 = fmaf(wD, __uint_as_float(uD << 16), acc3);
            acc4 = fmaf(wE2, __uint_as_float(uE2 << 16), acc4);
            acc5 = fmaf(wF, __uint_as_float(uF << 16), acc5);
            acc6 = fmaf(wG, __uint_as_float(uG << 16), acc6);
            acc7 = fmaf(wH2, __uint_as_float(uH2 << 16), acc7);
        }
        for (; j + 4 <= cnt; j += 4) {
            F40(A, j) F40(B, j + 1) F40(C, j + 2) F40(D, j + 3)
            acc0 = fmaf(wA, __uint_as_float(uA << 16), acc0);
            acc1 = fmaf(wB, __uint_as_float(uB << 16), acc1);
            acc2 = fmaf(wC, __uint_as_float(uC << 16), acc2);
            acc3 = fmaf(wD, __uint_as_float(uD << 16), acc3);
        }
        for (; j < cnt; ++j) {
            F40(A, j)
            acc0 = fmaf(wA, __uint_as_float(uA << 16), acc0);
        }
    }
    // reduce l across all lanes (each lane holds partial sum of its edges)
    #pragma unroll
    for (int off = 32; off > 0; off >>= 1) lpart += __shfl_xor(lpart, off);
    float l = lpart;
    float acc = ((acc0 + acc1) + (acc2 + acc3)) + ((acc4 + acc5) + (acc6 + acc7));
    // fused bias + log_softmax over the 40 class lanes
    float val = acc / (l + 1e-16f) + ((lane < 40) ? bias[lane] : 0.f);
    float mval = (lane < 40) ? val : -1e30f;
    #pragma unroll
    for (int off = 32; off > 0; off >>= 1)
        mval = fmaxf(mval, __shfl_xor(mval, off));
    float ex = (lane < 40) ? __expf(val - mval) : 0.f;
    #pragma unroll
    for (int off = 32; off > 0; off >>= 1) ex += __shfl_xor(ex, off);
    if (lane < 40)
        out[(size_t)node * 40 + lane] = val - mval - __logf(ex);
}

// =================== launch ===================

extern "C" void kernel_launch(void* const* d_in, const int* in_sizes, int n_in,
                              void* d_out, int out_size, void* d_ws,
                              size_t ws_size, hipStream_t stream) {
    const float* features = (const float*)d_in[0];
    const int* edge_index = (const int*)d_in[1];
    const float* W0 = (const float*)d_in[2];
    const float* as0 = (const float*)d_in[3];
    const float* ad0 = (const float*)d_in[4];
    const float* b0 = (const float*)d_in[5];
    const float* W1 = (const float*)d_in[6];
    const float* as1 = (const float*)d_in[7];
    const float* ad1 = (const float*)d_in[8];
    const float* b1 = (const float*)d_in[9];
    const float* W2 = (const float*)d_in[10];
    const float* as2 = (const float*)d_in[11];
    const float* ad2 = (const float*)d_in[12];
    const float* b2 = (const float*)d_in[13];

    int N = in_sizes[0] / 256;
    int E = in_sizes[1] / 2;
    int Etot = E + N;
    int nbuck = (N + 127) >> 7;  // 128-node buckets (<= MAXBUCK)
    const int* srcs = edge_index;
    const int* dsts = edge_index + E;

    // workspace layout
    float* ws = (float*)d_ws;
    float* Hbuf = ws;                              // N*64 floats (pairs scratch)
    float* Abuf = Hbuf + (size_t)N * 64;           // N*64 floats
    float* adb  = Abuf + (size_t)N * 64;           // N*8
    float* asb  = adb + (size_t)N * 8;             // N*8
    char* hrec  = (char*)(asb + (size_t)N * 8);    // N*128 bytes
    int* row_ptr = (int*)(hrec + (size_t)N * 128); // N+1
    int* bcnt    = row_ptr + (N + 2);              // MAXBUCK
    int* bptrE   = bcnt + MAXBUCK;                 // MAXBUCK
    int* bcurE   = bptrE + MAXBUCK;                // MAXBUCK
    int* csr_src = bcurE + MAXBUCK;                // Etot
    int* bhist   = csr_src + Etot;                 // gSc * MAXBUCK
    int* pairs   = (int*)Hbuf;                     // scratch, dead before gemm

    const int B = 256;
    int gAg = (N + 3) / 4;
    int gGm = (N + 63) / 64;
    int gSc = (E + EPB - 1) / EPB;

    // ---------- CSR build (all atomic frontiers bucket-level) ----------
    (void)hipMemsetAsync(bcnt, 0, MAXBUCK * 4, stream);
    bucket_hist_k<<<gSc, B, 0, stream>>>(dsts, bcnt, bhist, E, nbuck);
    bucket_scan_k<<<1, 512, 0, stream>>>(bcnt, bptrE, bcurE, nbuck);
    bscatter_k<<<gSc, B, 0, stream>>>(srcs, dsts, bhist, bcurE, pairs, E,
                                      nbuck);
    bucket_sort_k<<<nbuck, B, 0, stream>>>(pairs, bptrE, bcurE, row_ptr,
                                           csr_src, N, Etot);

    // ---------------- layer 0 ----------------
    gemm_pack8_k<256><<<gGm, B, 0, stream>>>(features, W0, as0, ad0, hrec,
                                             asb, adb, N);
    aggr64_k<<<gAg, B, 0, stream>>>(hrec, asb, adb, row_ptr, csr_src, b0,
                                    Abuf, N);

    // ---------------- layer 1 ----------------
    gemm_pack8_k<64><<<gGm, B, 0, stream>>>(Abuf, W1, as1, ad1, hrec, asb,
                                            adb, N);
    aggr64_k<<<gAg, B, 0, stream>>>(hrec, asb, adb, row_ptr, csr_src, b1,
                                    Abuf, N);

    // ---------------- layer 2 ----------------
    gemm_pack40_k<<<gGm, B, 0, stream>>>(Abuf, W2, as2, ad2, hrec, asb, adb,
                                         N);
    aggr40_k<<<gAg, B, 0, stream>>>(hrec, asb, adb, row_ptr, csr_src, b2,
                                    (float*)d_out, N);
}

// Round 6
// 575.106 us; speedup vs baseline: 1.9316x; 1.0078x over previous
//
#include <hip/hip_runtime.h>
#include <hip/hip_bf16.h>

#define NEG_SLOPE 0.2f
#define LOG2E 1.44269504f
#define EPB 8192      // edges per hist/scatter block
#define MAXBUCK 800   // >= ceil(N/128)

typedef __attribute__((ext_vector_type(8))) short short8;
typedef __attribute__((ext_vector_type(4))) float f32x4;

__device__ __forceinline__ unsigned short f2bf(float x) {
    unsigned u = __float_as_uint(x);
    unsigned r = (u + 0x7FFFu + ((u >> 16) & 1u)) >> 16;  // RNE
    return (unsigned short)r;
}

__device__ __forceinline__ float fexp2(float x) {
    return __builtin_amdgcn_exp2f(x);  // v_exp_f32: 2^x
}

__device__ __forceinline__ float readlane_f(float v, int l) {
    return __int_as_float(__builtin_amdgcn_readlane(__float_as_int(v), l));
}

// ===== CSR build: bucket(128-node) hist -> scan -> scatter -> LDS sort =====
// All global atomic frontiers are bucket-level (nbuck<=800 counters).
// csr_src holds BYTE offsets (s<<7) into the 128B-stride record tables.

__global__ __launch_bounds__(512) void bucket_hist_k(
    const int* __restrict__ dsts, int* __restrict__ bcnt,
    int* __restrict__ bhist, int E, int nbuck) {
    __shared__ int lh[MAXBUCK];
    int t = threadIdx.x;
    for (int i = t; i < nbuck; i += 512) lh[i] = 0;
    __syncthreads();
    int base = blockIdx.x * EPB;
    int cnt = E - base;
    if (cnt > EPB) cnt = EPB;
    int nq = cnt >> 2;
    const int4* d4p = (const int4*)(dsts + base);
    for (int i = t; i < nq; i += 512) {
        int4 d = d4p[i];
        atomicAdd(&lh[d.x >> 7], 1);
        atomicAdd(&lh[d.y >> 7], 1);
        atomicAdd(&lh[d.z >> 7], 1);
        atomicAdd(&lh[d.w >> 7], 1);
    }
    for (int i = (nq << 2) + t; i < cnt; i += 512)
        atomicAdd(&lh[dsts[base + i] >> 7], 1);
    __syncthreads();
    int* bh = bhist + (size_t)blockIdx.x * MAXBUCK;
    for (int i = t; i < nbuck; i += 512) {
        int c = lh[i];
        bh[i] = c;
        if (c) atomicAdd(&bcnt[i], c);
    }
}

// 1-block exclusive scan of bucket counts (nbuck <= 2048)
__global__ __launch_bounds__(512) void bucket_scan_k(
    const int* __restrict__ bcnt, int* __restrict__ bptrE,
    int* __restrict__ bcurE, int nbuck) {
    __shared__ int csum[512];
    int t = threadIdx.x;
    int i0 = t * 4;
    int v0 = 0, v1 = 0, v2 = 0, v3 = 0;
    if (i0 < nbuck) v0 = bcnt[i0];
    if (i0 + 1 < nbuck) v1 = bcnt[i0 + 1];
    if (i0 + 2 < nbuck) v2 = bcnt[i0 + 2];
    if (i0 + 3 < nbuck) v3 = bcnt[i0 + 3];
    int s = v0 + v1 + v2 + v3;
    csum[t] = s;
    __syncthreads();
    for (int off = 1; off < 512; off <<= 1) {
        int x = (t >= off) ? csum[t - off] : 0;
        __syncthreads();
        csum[t] += x;
        __syncthreads();
    }
    int base = csum[t] - s;
    if (i0 < nbuck)     { bptrE[i0] = base;     bcurE[i0] = base; }     base += v0;
    if (i0 + 1 < nbuck) { bptrE[i0 + 1] = base; bcurE[i0 + 1] = base; } base += v1;
    if (i0 + 2 < nbuck) { bptrE[i0 + 2] = base; bcurE[i0 + 2] = base; } base += v2;
    if (i0 + 3 < nbuck) { bptrE[i0 + 3] = base; bcurE[i0 + 3] = base; }
}

// packed scatter into bucket segments; per-block hist comes from bhist
__global__ __launch_bounds__(512) void bscatter_k(
    const int* __restrict__ srcs, const int* __restrict__ dsts,
    const int* __restrict__ bhist, int* __restrict__ bcurE,
    int* __restrict__ pairs, int E, int nbuck) {
    __shared__ int lh[MAXBUCK];
    __shared__ int lbase[MAXBUCK];
    int t = threadIdx.x;
    const int* bh = bhist + (size_t)blockIdx.x * MAXBUCK;
    for (int i = t; i < nbuck; i += 512) {
        int c = bh[i];
        lbase[i] = c ? atomicAdd(&bcurE[i], c) : 0;
        lh[i] = 0;
    }
    __syncthreads();
    int base = blockIdx.x * EPB;
    int cnt = E - base;
    if (cnt > EPB) cnt = EPB;
    int nq = cnt >> 2;
    const int4* d4p = (const int4*)(dsts + base);
    const int4* s4p = (const int4*)(srcs + base);
    for (int i = t; i < nq; i += 512) {
        int4 d = d4p[i];
        int4 s = s4p[i];
        int b0 = d.x >> 7, b1 = d.y >> 7, b2 = d.z >> 7, b3 = d.w >> 7;
        int r0 = atomicAdd(&lh[b0], 1);
        int r1 = atomicAdd(&lh[b1], 1);
        int r2 = atomicAdd(&lh[b2], 1);
        int r3 = atomicAdd(&lh[b3], 1);
        pairs[lbase[b0] + r0] = (s.x << 7) | (d.x & 127);
        pairs[lbase[b1] + r1] = (s.y << 7) | (d.y & 127);
        pairs[lbase[b2] + r2] = (s.z << 7) | (d.z & 127);
        pairs[lbase[b3] + r3] = (s.w << 7) | (d.w & 127);
    }
    for (int i = (nq << 2) + t; i < cnt; i += 512) {
        int s = srcs[base + i], d = dsts[base + i];
        int r = atomicAdd(&lh[d >> 7], 1);
        pairs[lbase[d >> 7] + r] = (s << 7) | (d & 127);
    }
}

// per-bucket: LDS hist(128) + scan -> row_ptr + self-loop + sorted csr_src
// csr_src entries are byte offsets (s<<7).
__global__ __launch_bounds__(256) void bucket_sort_k(
    const int* __restrict__ pairs, const int* __restrict__ bptrE,
    const int* __restrict__ bcurE, int* __restrict__ row_ptr,
    int* __restrict__ csr_src, int N, int Etot) {
    __shared__ int lh[128];
    __shared__ int sc[128];
    int b = blockIdx.x;
    int n0 = b << 7;
    int t = threadIdx.x;
    if (t < 128) lh[t] = 0;
    __syncthreads();
    int e0 = bptrE[b], e1 = bcurE[b];
    for (int e = e0 + t; e < e1; e += 256)
        atomicAdd(&lh[pairs[e] & 127], 1);
    __syncthreads();
    if (t < 128) sc[t] = lh[t];
    __syncthreads();
    for (int off = 1; off < 128; off <<= 1) {
        int x = (t < 128 && t >= off) ? sc[t - off] : 0;
        __syncthreads();
        if (t < 128) sc[t] += x;
        __syncthreads();
    }
    if (t < 128) {
        int cntv = lh[t];
        int excl = sc[t] - cntv;
        int n = n0 + t;
        int rp = e0 + n0 + t + excl;  // edges before n + self-loops before n
        if (n < N) {
            row_ptr[n] = rp;
            csr_src[rp] = n << 7;  // self-loop at slot 0 (byte offset)
        }
        lh[t] = rp + 1;  // cursor
    }
    __syncthreads();
    for (int e = e0 + t; e < e1; e += 256) {
        int p = pairs[e];
        int pos = atomicAdd(&lh[p & 127], 1);
        csr_src[pos] = p & ~127;  // s<<7
    }
    if (b == 0 && t == 0) row_ptr[N] = Etot;
}

// ====== fused MFMA GEMM + pack (COUT=64): x[N,K] @ W[K,64] -> hrec/asb/adb ==

template <int K>
__global__ __launch_bounds__(256) void gemm_pack8_k(
    const float* __restrict__ x, const float* __restrict__ W,
    const float* __restrict__ a_src, const float* __restrict__ a_dst,
    char* __restrict__ hrec, float* __restrict__ asb,
    float* __restrict__ adb, int N) {
    constexpr int NT = 4;
    constexpr int KT = K / 32;
    constexpr size_t WF_BYTES = (size_t)KT * NT * 64 * 8 * sizeof(short);
    constexpr size_t H_BYTES = (size_t)64 * 65 * sizeof(float);
    __shared__ alignas(16) char smem[WF_BYTES > H_BYTES ? WF_BYTES : H_BYTES];
    short* Wf = (short*)smem;
    float* hL = (float*)smem;
    int tid = threadIdx.x;
    for (int f = tid; f < KT * NT * 64; f += 256) {
        int lane = f & 63;
        int ntk = f >> 6;
        int nt = ntk % NT, kt = ntk / NT;
        int q = lane >> 4, c = lane & 15;
        int n = nt * 16 + c;
        int k0 = kt * 32 + q * 8;
        short8 frag;
        #pragma unroll
        for (int j = 0; j < 8; ++j)
            frag[j] = (short)f2bf(W[(size_t)(k0 + j) * 64 + n]);
        *(short8*)&Wf[f * 8] = frag;
    }
    __syncthreads();
    int wave = tid >> 6, lane = tid & 63;
    int q = lane >> 4, c = lane & 15;
    int m0 = blockIdx.x * 64 + wave * 16;
    int arow = m0 + c;
    int arl = arow < N ? arow : N - 1;
    f32x4 acc[NT] = {};
    for (int kt = 0; kt < KT; ++kt) {
        const float* xp = x + (size_t)arl * K + kt * 32 + q * 8;
        float4 a0 = *(const float4*)xp;
        float4 a1 = *(const float4*)(xp + 4);
        float av[8] = {a0.x, a0.y, a0.z, a0.w, a1.x, a1.y, a1.z, a1.w};
        short8 af;
        #pragma unroll
        for (int j = 0; j < 8; ++j) af[j] = (short)f2bf(av[j]);
        #pragma unroll
        for (int nt = 0; nt < NT; ++nt) {
            short8 bf = *(const short8*)&Wf[((kt * NT + nt) * 64 + lane) * 8];
            acc[nt] = __builtin_amdgcn_mfma_f32_16x16x32_bf16(af, bf, acc[nt],
                                                              0, 0, 0);
        }
    }
    __syncthreads();  // all waves done reading Wf; reuse as hL
    int lrow = wave * 16 + q * 4;
    #pragma unroll
    for (int nt = 0; nt < NT; ++nt)
        #pragma unroll
        for (int reg = 0; reg < 4; ++reg)
            hL[(lrow + reg) * 65 + nt * 16 + c] = acc[nt][reg];
    __syncthreads();
    #pragma unroll
    for (int it = 0; it < 2; ++it) {
        int id = it * 256 + tid;  // 0..511 = (node 0..63) x (head 0..7)
        int ln = id >> 3, hd = id & 7;
        int gn = blockIdx.x * 64 + ln;
        if (gn >= N) continue;
        const float* hp = &hL[ln * 65 + hd * 8];
        float as = 0.f, ad = 0.f;
        float hv[8];
        #pragma unroll
        for (int j = 0; j < 8; ++j) {
            hv[j] = hp[j];
            as += hv[j] * a_src[hd * 8 + j];
            ad += hv[j] * a_dst[hd * 8 + j];
        }
        adb[gn * 8 + hd] = ad * LOG2E;
        asb[gn * 8 + hd] = as * LOG2E;
        unsigned short u[8];
        #pragma unroll
        for (int j = 0; j < 8; ++j) u[j] = f2bf(hv[j]);
        uint4 pk;
        pk.x = (unsigned)u[0] | ((unsigned)u[1] << 16);
        pk.y = (unsigned)u[2] | ((unsigned)u[3] << 16);
        pk.z = (unsigned)u[4] | ((unsigned)u[5] << 16);
        pk.w = (unsigned)u[6] | ((unsigned)u[7] << 16);
        *(uint4*)(hrec + (size_t)gn * 128 + hd * 16) = pk;
    }
}

// ====== fused MFMA GEMM + pack40 (layer 2): 128 B records, as at +80 ======

__global__ __launch_bounds__(256) void gemm_pack40_k(
    const float* __restrict__ x, const float* __restrict__ W,
    const float* __restrict__ a_src, const float* __restrict__ a_dst,
    char* __restrict__ rec40, float* __restrict__ adb, int N) {
    constexpr int K = 64, NT = 3, KT = 2;
    constexpr size_t WF_BYTES = (size_t)KT * NT * 64 * 8 * sizeof(short);
    constexpr size_t H_BYTES = (size_t)64 * 41 * sizeof(float);
    __shared__ alignas(16) char smem[WF_BYTES > H_BYTES ? WF_BYTES : H_BYTES];
    short* Wf = (short*)smem;
    float* hL = (float*)smem;
    int tid = threadIdx.x;
    for (int f = tid; f < KT * NT * 64; f += 256) {
        int lane = f & 63;
        int ntk = f >> 6;
        int nt = ntk % NT, kt = ntk / NT;
        int q = lane >> 4, c = lane & 15;
        int n = nt * 16 + c;
        int k0 = kt * 32 + q * 8;
        short8 frag;
        #pragma unroll
        for (int j = 0; j < 8; ++j) {
            float v = (n < 40) ? W[(size_t)(k0 + j) * 40 + n] : 0.f;
            frag[j] = (short)f2bf(v);
        }
        *(short8*)&Wf[f * 8] = frag;
    }
    __syncthreads();
    int wave = tid >> 6, lane = tid & 63;
    int q = lane >> 4, c = lane & 15;
    int m0 = blockIdx.x * 64 + wave * 16;
    int arow = m0 + c;
    int arl = arow < N ? arow : N - 1;
    f32x4 acc[NT] = {};
    for (int kt = 0; kt < KT; ++kt) {
        const float* xp = x + (size_t)arl * K + kt * 32 + q * 8;
        float4 a0 = *(const float4*)xp;
        float4 a1 = *(const float4*)(xp + 4);
        float av[8] = {a0.x, a0.y, a0.z, a0.w, a1.x, a1.y, a1.z, a1.w};
        short8 af;
        #pragma unroll
        for (int j = 0; j < 8; ++j) af[j] = (short)f2bf(av[j]);
        #pragma unroll
        for (int nt = 0; nt < NT; ++nt) {
            short8 bf = *(const short8*)&Wf[((kt * NT + nt) * 64 + lane) * 8];
            acc[nt] = __builtin_amdgcn_mfma_f32_16x16x32_bf16(af, bf, acc[nt],
                                                              0, 0, 0);
        }
    }
    __syncthreads();
    int lrow = wave * 16 + q * 4;
    #pragma unroll
    for (int nt = 0; nt < NT; ++nt) {
        int n = nt * 16 + c;
        if (n >= 40) continue;
        #pragma unroll
        for (int reg = 0; reg < 4; ++reg)
            hL[(lrow + reg) * 41 + n] = acc[nt][reg];
    }
    __syncthreads();
    // 4 threads per node compute pas/pad
    int ln = tid >> 2, sub = tid & 3;
    int gn = blockIdx.x * 64 + ln;
    float pas = 0.f, pad = 0.f;
    if (gn < N) {
        for (int j = sub; j < 40; j += 4) {
            float hv = hL[ln * 41 + j];
            pas += hv * a_src[j];
            pad += hv * a_dst[j];
        }
    }
    pas += __shfl_xor(pas, 1); pas += __shfl_xor(pas, 2);
    pad += __shfl_xor(pad, 1); pad += __shfl_xor(pad, 2);
    if (gn < N && sub == 0) {
        *(float*)(rec40 + (size_t)gn * 128 + 80) = pas * LOG2E;
        adb[gn] = pad * LOG2E;
    }
    // write bf16 h, stride 128 B
    for (int i = tid; i < 64 * 40; i += 256) {
        int n2 = i / 40, ch = i % 40;
        int g2 = blockIdx.x * 64 + n2;
        if (g2 < N)
            *(unsigned short*)(rec40 + (size_t)g2 * 128 + ch * 2) =
                f2bf(hL[n2 * 41 + ch]);
    }
}

// ======= aggr64: parallel weight phase + LDS broadcast; zero-padded loop ====
// csr_src entries are byte offsets (s<<7) -> no per-edge address shift.

#define EDGE64(SUF, IDX)                                                     \
    int s##SUF = __builtin_amdgcn_readlane(sv, (IDX));                       \
    float w##SUF = lwp[(IDX)];                                               \
    unsigned u##SUF =                                                        \
        *(const unsigned short*)(hrec + (size_t)(unsigned)s##SUF + lane2);

__global__ __launch_bounds__(256) void aggr64_k(
    const char* __restrict__ hrec, const float* __restrict__ asb,
    const float* __restrict__ adb, const int* __restrict__ row_ptr,
    const int* __restrict__ csr_src, const float* __restrict__ bias,
    float* __restrict__ out, int N) {
    __shared__ float wlds[4 * 1040];  // 4 waves x 2 buffers x (8*65)
    int wave = threadIdx.x >> 6;
    int node = blockIdx.x * 4 + wave;
    if (node >= N) return;
    int lane = threadIdx.x & 63;
    int hd = lane >> 3;
    int lane2 = lane * 2;
    float* wbA = wlds + wave * 1040;
    float* wbB = wbA + 520;
    const float* lwpA = wbA + hd * 65;
    const float* lwpB = wbB + hd * 65;
    int beg = row_ptr[node], end = row_ptr[node + 1];
    float4 adv0 = *(const float4*)(adb + (size_t)node * 8);
    float4 adv1 = *(const float4*)(adb + (size_t)node * 8 + 4);
    float acc0 = 0.f, acc1 = 0.f, acc2 = 0.f, acc3 = 0.f;
    float acc4 = 0.f, acc5 = 0.f, acc6 = 0.f, acc7 = 0.f;
    float l0 = 0.f, l1 = 0.f, l2 = 0.f, l3 = 0.f;
    float l4 = 0.f, l5 = 0.f, l6 = 0.f, l7 = 0.f;
    int par = 0;
    for (int i0 = beg; i0 < end; i0 += 64, par ^= 1) {
        int tail = end - i0;
        int sv = csr_src[i0 + (lane < tail ? lane : 0)];  // byte offset s<<7
        int cnt = tail < 64 ? tail : 64;
        float* wb = par ? wbB : wbA;
        const float* lwp = par ? lwpB : lwpA;
        // ---- parallel weight phase: this lane's edge, all 8 heads ----
        {
            const float* asp =
                (const float*)((const char*)asb + (((unsigned)sv) >> 2));
            float4 s0 = *(const float4*)asp;
            float4 s1 = *(const float4*)(asp + 4);
            float w0 = s0.x + adv0.x; w0 = fmaxf(w0, NEG_SLOPE * w0); w0 = fexp2(w0);
            float w1 = s0.y + adv0.y; w1 = fmaxf(w1, NEG_SLOPE * w1); w1 = fexp2(w1);
            float w2 = s0.z + adv0.z; w2 = fmaxf(w2, NEG_SLOPE * w2); w2 = fexp2(w2);
            float w3 = s0.w + adv0.w; w3 = fmaxf(w3, NEG_SLOPE * w3); w3 = fexp2(w3);
            float w4 = s1.x + adv1.x; w4 = fmaxf(w4, NEG_SLOPE * w4); w4 = fexp2(w4);
            float w5 = s1.y + adv1.y; w5 = fmaxf(w5, NEG_SLOPE * w5); w5 = fexp2(w5);
            float w6 = s1.z + adv1.z; w6 = fmaxf(w6, NEG_SLOPE * w6); w6 = fexp2(w6);
            float w7 = s1.w + adv1.w; w7 = fmaxf(w7, NEG_SLOPE * w7); w7 = fexp2(w7);
            if (lane >= cnt) {  // zero-pad: single 8-stride fma loop below
                w0 = 0.f; w1 = 0.f; w2 = 0.f; w3 = 0.f;
                w4 = 0.f; w5 = 0.f; w6 = 0.f; w7 = 0.f;
            }
            wb[lane]       = w0;
            wb[65 + lane]  = w1;
            wb[130 + lane] = w2;
            wb[195 + lane] = w3;
            wb[260 + lane] = w4;
            wb[325 + lane] = w5;
            wb[390 + lane] = w6;
            wb[455 + lane] = w7;
        }
        // ---- fma phase: w via LDS broadcast (zeros beyond cnt) ----
        for (int j = 0; j < cnt; j += 8) {
            EDGE64(A, j)      EDGE64(B, j + 1) EDGE64(C, j + 2) EDGE64(D, j + 3)
            EDGE64(E2, j + 4) EDGE64(F, j + 5) EDGE64(G, j + 6) EDGE64(H2, j + 7)
            l0 += wA; l1 += wB; l2 += wC; l3 += wD;
            l4 += wE2; l5 += wF; l6 += wG; l7 += wH2;
            acc0 = fmaf(wA, __uint_as_float(uA << 16), acc0);
            acc1 = fmaf(wB, __uint_as_float(uB << 16), acc1);
            acc2 = fmaf(wC, __uint_as_float(uC << 16), acc2);
            acc3 = fmaf(wD, __uint_as_float(uD << 16), acc3);
            acc4 = fmaf(wE2, __uint_as_float(uE2 << 16), acc4);
            acc5 = fmaf(wF, __uint_as_float(uF << 16), acc5);
            acc6 = fmaf(wG, __uint_as_float(uG << 16), acc6);
            acc7 = fmaf(wH2, __uint_as_float(uH2 << 16), acc7);
        }
    }
    float l = ((l0 + l1) + (l2 + l3)) + ((l4 + l5) + (l6 + l7));
    float acc = ((acc0 + acc1) + (acc2 + acc3)) + ((acc4 + acc5) + (acc6 + acc7));
    out[(size_t)node * 64 + lane] = acc / (l + 1e-16f) + bias[lane];
}

// ======= aggr40: parallel weight phase + readlane fma; zero-padded loop =====

#define F40(SUF, IDX)                                                        \
    int s##SUF = __builtin_amdgcn_readlane(sv, (IDX));                       \
    float w##SUF = readlane_f(wv, (IDX));                                    \
    unsigned u##SUF =                                                        \
        *(const unsigned short*)(rec40 + (size_t)(unsigned)s##SUF + cl2);

__global__ __launch_bounds__(256) void aggr40_k(
    const char* __restrict__ rec40, const float* __restrict__ adb,
    const int* __restrict__ row_ptr, const int* __restrict__ csr_src,
    const float* __restrict__ bias, float* __restrict__ out, int N) {
    int node = blockIdx.x * 4 + (threadIdx.x >> 6);
    if (node >= N) return;
    int lane = threadIdx.x & 63;
    int cl2 = (lane < 40 ? lane : 0) * 2;
    int beg = row_ptr[node], end = row_ptr[node + 1];
    float ad = adb[node];
    float acc0 = 0.f, acc1 = 0.f, acc2 = 0.f, acc3 = 0.f;
    float acc4 = 0.f, acc5 = 0.f, acc6 = 0.f, acc7 = 0.f;
    float lpart = 0.f;
    for (int i0 = beg; i0 < end; i0 += 64) {
        int tail = end - i0;
        int sv = csr_src[i0 + (lane < tail ? lane : 0)];  // byte offset s<<7
        int cnt = tail < 64 ? tail : 64;
        // ---- parallel weight phase: lane computes its own edge's weight ----
        float as = *(const float*)(rec40 + (size_t)(unsigned)sv + 80);
        float v = as + ad;
        v = fmaxf(v, NEG_SLOPE * v);
        float wv = fexp2(v);
        wv = (lane < cnt) ? wv : 0.f;
        lpart += wv;
        // ---- fma phase: zeros beyond cnt make padding exact ----
        for (int j = 0; j < cnt; j += 8) {
            F40(A, j)     F40(B, j + 1) F40(C, j + 2) F40(D, j + 3)
            F40(E2, j + 4) F40(F, j + 5) F40(G, j + 6) F40(H2, j + 7)
            acc0 = fmaf(wA, __uint_as_float(uA << 16), acc0);
            acc1 = fmaf(wB, __uint_as_float(uB << 16), acc1);
            acc2 = fmaf(wC, __uint_as_float(uC << 16), acc2);
            acc3 = fmaf(wD, __uint_as_float(uD << 16), acc3);
            acc4 = fmaf(wE2, __uint_as_float(uE2 << 16), acc4);
            acc5 = fmaf(wF, __uint_as_float(uF << 16), acc5);
            acc6 = fmaf(wG, __uint_as_float(uG << 16), acc6);
            acc7 = fmaf(wH2, __uint_as_float(uH2 << 16), acc7);
        }
    }
    // reduce l across all lanes (each lane holds partial sum of its edges)
    #pragma unroll
    for (int off = 32; off > 0; off >>= 1) lpart += __shfl_xor(lpart, off);
    float l = lpart;
    float acc = ((acc0 + acc1) + (acc2 + acc3)) + ((acc4 + acc5) + (acc6 + acc7));
    // fused bias + log_softmax over the 40 class lanes
    float val = acc / (l + 1e-16f) + ((lane < 40) ? bias[lane] : 0.f);
    float mval = (lane < 40) ? val : -1e30f;
    #pragma unroll
    for (int off = 32; off > 0; off >>= 1)
        mval = fmaxf(mval, __shfl_xor(mval, off));
    float ex = (lane < 40) ? __expf(val - mval) : 0.f;
    #pragma unroll
    for (int off = 32; off > 0; off >>= 1) ex += __shfl_xor(ex, off);
    if (lane < 40)
        out[(size_t)node * 40 + lane] = val - mval - __logf(ex);
}

// =================== launch ===================

extern "C" void kernel_launch(void* const* d_in, const int* in_sizes, int n_in,
                              void* d_out, int out_size, void* d_ws,
                              size_t ws_size, hipStream_t stream) {
    const float* features = (const float*)d_in[0];
    const int* edge_index = (const int*)d_in[1];
    const float* W0 = (const float*)d_in[2];
    const float* as0 = (const float*)d_in[3];
    const float* ad0 = (const float*)d_in[4];
    const float* b0 = (const float*)d_in[5];
    const float* W1 = (const float*)d_in[6];
    const float* as1 = (const float*)d_in[7];
    const float* ad1 = (const float*)d_in[8];
    const float* b1 = (const float*)d_in[9];
    const float* W2 = (const float*)d_in[10];
    const float* as2 = (const float*)d_in[11];
    const float* ad2 = (const float*)d_in[12];
    const float* b2 = (const float*)d_in[13];

    int N = in_sizes[0] / 256;
    int E = in_sizes[1] / 2;
    int Etot = E + N;
    int nbuck = (N + 127) >> 7;  // 128-node buckets (<= MAXBUCK)
    const int* srcs = edge_index;
    const int* dsts = edge_index + E;

    // workspace layout
    float* ws = (float*)d_ws;
    float* Hbuf = ws;                              // N*64 floats (pairs scratch)
    float* Abuf = Hbuf + (size_t)N * 64;           // N*64 floats
    float* adb  = Abuf + (size_t)N * 64;           // N*8
    float* asb  = adb + (size_t)N * 8;             // N*8
    char* hrec  = (char*)(asb + (size_t)N * 8);    // N*128 bytes
    int* row_ptr = (int*)(hrec + (size_t)N * 128); // N+1
    int* bcnt    = row_ptr + (N + 2);              // MAXBUCK
    int* bptrE   = bcnt + MAXBUCK;                 // MAXBUCK
    int* bcurE   = bptrE + MAXBUCK;                // MAXBUCK
    int* csr_src = bcurE + MAXBUCK;                // Etot
    int* bhist   = csr_src + Etot;                 // gSc * MAXBUCK
    int* pairs   = (int*)Hbuf;                     // scratch, dead before gemm

    const int B = 256;
    int gAg = (N + 3) / 4;
    int gGm = (N + 63) / 64;
    int gSc = (E + EPB - 1) / EPB;

    // ---------- CSR build (all atomic frontiers bucket-level) ----------
    (void)hipMemsetAsync(bcnt, 0, MAXBUCK * 4, stream);
    bucket_hist_k<<<gSc, 512, 0, stream>>>(dsts, bcnt, bhist, E, nbuck);
    bucket_scan_k<<<1, 512, 0, stream>>>(bcnt, bptrE, bcurE, nbuck);
    bscatter_k<<<gSc, 512, 0, stream>>>(srcs, dsts, bhist, bcurE, pairs, E,
                                        nbuck);
    bucket_sort_k<<<nbuck, B, 0, stream>>>(pairs, bptrE, bcurE, row_ptr,
                                           csr_src, N, Etot);

    // ---------------- layer 0 ----------------
    gemm_pack8_k<256><<<gGm, B, 0, stream>>>(features, W0, as0, ad0, hrec,
                                             asb, adb, N);
    aggr64_k<<<gAg, B, 0, stream>>>(hrec, asb, adb, row_ptr, csr_src, b0,
                                    Abuf, N);

    // ---------------- layer 1 ----------------
    gemm_pack8_k<64><<<gGm, B, 0, stream>>>(Abuf, W1, as1, ad1, hrec, asb,
                                            adb, N);
    aggr64_k<<<gAg, B, 0, stream>>>(hrec, asb, adb, row_ptr, csr_src, b1,
                                    Abuf, N);

    // ---------------- layer 2 ----------------
    gemm_pack40_k<<<gGm, B, 0, stream>>>(Abuf, W2, as2, ad2, hrec, adb, N);
    aggr40_k<<<gAg, B, 0, stream>>>(hrec, adb, row_ptr, csr_src, b2,
                                    (float*)d_out, N);
}

// Round 7
// 552.147 us; speedup vs baseline: 2.0119x; 1.0416x over previous
//
#include <hip/hip_runtime.h>
#include <hip/hip_bf16.h>

#define NEG_SLOPE 0.2f
#define LOG2E 1.44269504f
#define EPB 8192      // edges per hist/scatter block
#define MAXBUCK 800   // >= ceil(N/128)

typedef __attribute__((ext_vector_type(8))) short short8;
typedef __attribute__((ext_vector_type(4))) float f32x4;

__device__ __forceinline__ unsigned short f2bf(float x) {
    unsigned u = __float_as_uint(x);
    unsigned r = (u + 0x7FFFu + ((u >> 16) & 1u)) >> 16;  // RNE
    return (unsigned short)r;
}

__device__ __forceinline__ float fexp2(float x) {
    return __builtin_amdgcn_exp2f(x);  // v_exp_f32: 2^x
}

// ===== CSR build: bucket(128-node) hist -> scan -> scatter -> LDS sort =====
// All global atomic frontiers are bucket-level (nbuck<=800 counters).
// csr_src holds BYTE offsets (s<<7) into the 128B-stride record tables.

__global__ __launch_bounds__(512) void bucket_hist_k(
    const int* __restrict__ dsts, int* __restrict__ bcnt,
    int* __restrict__ bhist, int E, int nbuck) {
    __shared__ int lh[MAXBUCK];
    int t = threadIdx.x;
    for (int i = t; i < nbuck; i += 512) lh[i] = 0;
    __syncthreads();
    int base = blockIdx.x * EPB;
    int cnt = E - base;
    if (cnt > EPB) cnt = EPB;
    int nq = cnt >> 2;
    const int4* d4p = (const int4*)(dsts + base);
    for (int i = t; i < nq; i += 512) {
        int4 d = d4p[i];
        atomicAdd(&lh[d.x >> 7], 1);
        atomicAdd(&lh[d.y >> 7], 1);
        atomicAdd(&lh[d.z >> 7], 1);
        atomicAdd(&lh[d.w >> 7], 1);
    }
    for (int i = (nq << 2) + t; i < cnt; i += 512)
        atomicAdd(&lh[dsts[base + i] >> 7], 1);
    __syncthreads();
    int* bh = bhist + (size_t)blockIdx.x * MAXBUCK;
    for (int i = t; i < nbuck; i += 512) {
        int c = lh[i];
        bh[i] = c;
        if (c) atomicAdd(&bcnt[i], c);
    }
}

// 1-block exclusive scan of bucket counts (nbuck <= 2048)
__global__ __launch_bounds__(512) void bucket_scan_k(
    const int* __restrict__ bcnt, int* __restrict__ bptrE,
    int* __restrict__ bcurE, int nbuck) {
    __shared__ int csum[512];
    int t = threadIdx.x;
    int i0 = t * 4;
    int v0 = 0, v1 = 0, v2 = 0, v3 = 0;
    if (i0 < nbuck) v0 = bcnt[i0];
    if (i0 + 1 < nbuck) v1 = bcnt[i0 + 1];
    if (i0 + 2 < nbuck) v2 = bcnt[i0 + 2];
    if (i0 + 3 < nbuck) v3 = bcnt[i0 + 3];
    int s = v0 + v1 + v2 + v3;
    csum[t] = s;
    __syncthreads();
    for (int off = 1; off < 512; off <<= 1) {
        int x = (t >= off) ? csum[t - off] : 0;
        __syncthreads();
        csum[t] += x;
        __syncthreads();
    }
    int base = csum[t] - s;
    if (i0 < nbuck)     { bptrE[i0] = base;     bcurE[i0] = base; }     base += v0;
    if (i0 + 1 < nbuck) { bptrE[i0 + 1] = base; bcurE[i0 + 1] = base; } base += v1;
    if (i0 + 2 < nbuck) { bptrE[i0 + 2] = base; bcurE[i0 + 2] = base; } base += v2;
    if (i0 + 3 < nbuck) { bptrE[i0 + 3] = base; bcurE[i0 + 3] = base; }
}

// packed scatter into bucket segments; per-block hist comes from bhist
__global__ __launch_bounds__(512) void bscatter_k(
    const int* __restrict__ srcs, const int* __restrict__ dsts,
    const int* __restrict__ bhist, int* __restrict__ bcurE,
    int* __restrict__ pairs, int E, int nbuck) {
    __shared__ int lh[MAXBUCK];
    __shared__ int lbase[MAXBUCK];
    int t = threadIdx.x;
    const int* bh = bhist + (size_t)blockIdx.x * MAXBUCK;
    for (int i = t; i < nbuck; i += 512) {
        int c = bh[i];
        lbase[i] = c ? atomicAdd(&bcurE[i], c) : 0;
        lh[i] = 0;
    }
    __syncthreads();
    int base = blockIdx.x * EPB;
    int cnt = E - base;
    if (cnt > EPB) cnt = EPB;
    int nq = cnt >> 2;
    const int4* d4p = (const int4*)(dsts + base);
    const int4* s4p = (const int4*)(srcs + base);
    for (int i = t; i < nq; i += 512) {
        int4 d = d4p[i];
        int4 s = s4p[i];
        int b0 = d.x >> 7, b1 = d.y >> 7, b2 = d.z >> 7, b3 = d.w >> 7;
        int r0 = atomicAdd(&lh[b0], 1);
        int r1 = atomicAdd(&lh[b1], 1);
        int r2 = atomicAdd(&lh[b2], 1);
        int r3 = atomicAdd(&lh[b3], 1);
        pairs[lbase[b0] + r0] = (s.x << 7) | (d.x & 127);
        pairs[lbase[b1] + r1] = (s.y << 7) | (d.y & 127);
        pairs[lbase[b2] + r2] = (s.z << 7) | (d.z & 127);
        pairs[lbase[b3] + r3] = (s.w << 7) | (d.w & 127);
    }
    for (int i = (nq << 2) + t; i < cnt; i += 512) {
        int s = srcs[base + i], d = dsts[base + i];
        int r = atomicAdd(&lh[d >> 7], 1);
        pairs[lbase[d >> 7] + r] = (s << 7) | (d & 127);
    }
}

// per-bucket: LDS hist(128) + scan -> row_ptr + self-loop + sorted csr_src
// csr_src entries are byte offsets (s<<7).
__global__ __launch_bounds__(256) void bucket_sort_k(
    const int* __restrict__ pairs, const int* __restrict__ bptrE,
    const int* __restrict__ bcurE, int* __restrict__ row_ptr,
    int* __restrict__ csr_src, int N, int Etot) {
    __shared__ int lh[128];
    __shared__ int sc[128];
    int b = blockIdx.x;
    int n0 = b << 7;
    int t = threadIdx.x;
    if (t < 128) lh[t] = 0;
    __syncthreads();
    int e0 = bptrE[b], e1 = bcurE[b];
    for (int e = e0 + t; e < e1; e += 256)
        atomicAdd(&lh[pairs[e] & 127], 1);
    __syncthreads();
    if (t < 128) sc[t] = lh[t];
    __syncthreads();
    for (int off = 1; off < 128; off <<= 1) {
        int x = (t < 128 && t >= off) ? sc[t - off] : 0;
        __syncthreads();
        if (t < 128) sc[t] += x;
        __syncthreads();
    }
    if (t < 128) {
        int cntv = lh[t];
        int excl = sc[t] - cntv;
        int n = n0 + t;
        int rp = e0 + n0 + t + excl;  // edges before n + self-loops before n
        if (n < N) {
            row_ptr[n] = rp;
            csr_src[rp] = n << 7;  // self-loop at slot 0 (byte offset)
        }
        lh[t] = rp + 1;  // cursor
    }
    __syncthreads();
    for (int e = e0 + t; e < e1; e += 256) {
        int p = pairs[e];
        int pos = atomicAdd(&lh[p & 127], 1);
        csr_src[pos] = p & ~127;  // s<<7
    }
    if (b == 0 && t == 0) row_ptr[N] = Etot;
}

// ====== fused MFMA GEMM + pack (COUT=64): x[N,K] @ W[K,64] -> hrec/asb/adb ==

template <int K>
__global__ __launch_bounds__(256) void gemm_pack8_k(
    const float* __restrict__ x, const float* __restrict__ W,
    const float* __restrict__ a_src, const float* __restrict__ a_dst,
    char* __restrict__ hrec, float* __restrict__ asb,
    float* __restrict__ adb, int N) {
    constexpr int NT = 4;
    constexpr int KT = K / 32;
    constexpr size_t WF_BYTES = (size_t)KT * NT * 64 * 8 * sizeof(short);
    constexpr size_t H_BYTES = (size_t)64 * 65 * sizeof(float);
    __shared__ alignas(16) char smem[WF_BYTES > H_BYTES ? WF_BYTES : H_BYTES];
    short* Wf = (short*)smem;
    float* hL = (float*)smem;
    int tid = threadIdx.x;
    for (int f = tid; f < KT * NT * 64; f += 256) {
        int lane = f & 63;
        int ntk = f >> 6;
        int nt = ntk % NT, kt = ntk / NT;
        int q = lane >> 4, c = lane & 15;
        int n = nt * 16 + c;
        int k0 = kt * 32 + q * 8;
        short8 frag;
        #pragma unroll
        for (int j = 0; j < 8; ++j)
            frag[j] = (short)f2bf(W[(size_t)(k0 + j) * 64 + n]);
        *(short8*)&Wf[f * 8] = frag;
    }
    __syncthreads();
    int wave = tid >> 6, lane = tid & 63;
    int q = lane >> 4, c = lane & 15;
    int m0 = blockIdx.x * 64 + wave * 16;
    int arow = m0 + c;
    int arl = arow < N ? arow : N - 1;
    f32x4 acc[NT] = {};
    for (int kt = 0; kt < KT; ++kt) {
        const float* xp = x + (size_t)arl * K + kt * 32 + q * 8;
        float4 a0 = *(const float4*)xp;
        float4 a1 = *(const float4*)(xp + 4);
        float av[8] = {a0.x, a0.y, a0.z, a0.w, a1.x, a1.y, a1.z, a1.w};
        short8 af;
        #pragma unroll
        for (int j = 0; j < 8; ++j) af[j] = (short)f2bf(av[j]);
        #pragma unroll
        for (int nt = 0; nt < NT; ++nt) {
            short8 bf = *(const short8*)&Wf[((kt * NT + nt) * 64 + lane) * 8];
            acc[nt] = __builtin_amdgcn_mfma_f32_16x16x32_bf16(af, bf, acc[nt],
                                                              0, 0, 0);
        }
    }
    __syncthreads();  // all waves done reading Wf; reuse as hL
    int lrow = wave * 16 + q * 4;
    #pragma unroll
    for (int nt = 0; nt < NT; ++nt)
        #pragma unroll
        for (int reg = 0; reg < 4; ++reg)
            hL[(lrow + reg) * 65 + nt * 16 + c] = acc[nt][reg];
    __syncthreads();
    #pragma unroll
    for (int it = 0; it < 2; ++it) {
        int id = it * 256 + tid;  // 0..511 = (node 0..63) x (head 0..7)
        int ln = id >> 3, hd = id & 7;
        int gn = blockIdx.x * 64 + ln;
        if (gn >= N) continue;
        const float* hp = &hL[ln * 65 + hd * 8];
        float as = 0.f, ad = 0.f;
        float hv[8];
        #pragma unroll
        for (int j = 0; j < 8; ++j) {
            hv[j] = hp[j];
            as += hv[j] * a_src[hd * 8 + j];
            ad += hv[j] * a_dst[hd * 8 + j];
        }
        adb[gn * 8 + hd] = ad * LOG2E;
        asb[gn * 8 + hd] = as * LOG2E;
        unsigned short u[8];
        #pragma unroll
        for (int j = 0; j < 8; ++j) u[j] = f2bf(hv[j]);
        uint4 pk;
        pk.x = (unsigned)u[0] | ((unsigned)u[1] << 16);
        pk.y = (unsigned)u[2] | ((unsigned)u[3] << 16);
        pk.z = (unsigned)u[4] | ((unsigned)u[5] << 16);
        pk.w = (unsigned)u[6] | ((unsigned)u[7] << 16);
        *(uint4*)(hrec + (size_t)gn * 128 + hd * 16) = pk;
    }
}

// ====== fused MFMA GEMM + pack40 (layer 2): 128 B records, as at +80 ======

__global__ __launch_bounds__(256) void gemm_pack40_k(
    const float* __restrict__ x, const float* __restrict__ W,
    const float* __restrict__ a_src, const float* __restrict__ a_dst,
    char* __restrict__ rec40, float* __restrict__ adb, int N) {
    constexpr int K = 64, NT = 3, KT = 2;
    constexpr size_t WF_BYTES = (size_t)KT * NT * 64 * 8 * sizeof(short);
    constexpr size_t H_BYTES = (size_t)64 * 41 * sizeof(float);
    __shared__ alignas(16) char smem[WF_BYTES > H_BYTES ? WF_BYTES : H_BYTES];
    short* Wf = (short*)smem;
    float* hL = (float*)smem;
    int tid = threadIdx.x;
    for (int f = tid; f < KT * NT * 64; f += 256) {
        int lane = f & 63;
        int ntk = f >> 6;
        int nt = ntk % NT, kt = ntk / NT;
        int q = lane >> 4, c = lane & 15;
        int n = nt * 16 + c;
        int k0 = kt * 32 + q * 8;
        short8 frag;
        #pragma unroll
        for (int j = 0; j < 8; ++j) {
            float v = (n < 40) ? W[(size_t)(k0 + j) * 40 + n] : 0.f;
            frag[j] = (short)f2bf(v);
        }
        *(short8*)&Wf[f * 8] = frag;
    }
    __syncthreads();
    int wave = tid >> 6, lane = tid & 63;
    int q = lane >> 4, c = lane & 15;
    int m0 = blockIdx.x * 64 + wave * 16;
    int arow = m0 + c;
    int arl = arow < N ? arow : N - 1;
    f32x4 acc[NT] = {};
    for (int kt = 0; kt < KT; ++kt) {
        const float* xp = x + (size_t)arl * K + kt * 32 + q * 8;
        float4 a0 = *(const float4*)xp;
        float4 a1 = *(const float4*)(xp + 4);
        float av[8] = {a0.x, a0.y, a0.z, a0.w, a1.x, a1.y, a1.z, a1.w};
        short8 af;
        #pragma unroll
        for (int j = 0; j < 8; ++j) af[j] = (short)f2bf(av[j]);
        #pragma unroll
        for (int nt = 0; nt < NT; ++nt) {
            short8 bf = *(const short8*)&Wf[((kt * NT + nt) * 64 + lane) * 8];
            acc[nt] = __builtin_amdgcn_mfma_f32_16x16x32_bf16(af, bf, acc[nt],
                                                              0, 0, 0);
        }
    }
    __syncthreads();
    int lrow = wave * 16 + q * 4;
    #pragma unroll
    for (int nt = 0; nt < NT; ++nt) {
        int n = nt * 16 + c;
        if (n >= 40) continue;
        #pragma unroll
        for (int reg = 0; reg < 4; ++reg)
            hL[(lrow + reg) * 41 + n] = acc[nt][reg];
    }
    __syncthreads();
    // 4 threads per node compute pas/pad
    int ln = tid >> 2, sub = tid & 3;
    int gn = blockIdx.x * 64 + ln;
    float pas = 0.f, pad = 0.f;
    if (gn < N) {
        for (int j = sub; j < 40; j += 4) {
            float hv = hL[ln * 41 + j];
            pas += hv * a_src[j];
            pad += hv * a_dst[j];
        }
    }
    pas += __shfl_xor(pas, 1); pas += __shfl_xor(pas, 2);
    pad += __shfl_xor(pad, 1); pad += __shfl_xor(pad, 2);
    if (gn < N && sub == 0) {
        *(float*)(rec40 + (size_t)gn * 128 + 80) = pas * LOG2E;
        adb[gn] = pad * LOG2E;
    }
    // write bf16 h, stride 128 B
    for (int i = tid; i < 64 * 40; i += 256) {
        int n2 = i / 40, ch = i % 40;
        int g2 = blockIdx.x * 64 + n2;
        if (g2 < N)
            *(unsigned short*)(rec40 + (size_t)g2 * 128 + ch * 2) =
                f2bf(hL[n2 * 41 + ch]);
    }
}

// ======= aggr64: 8 edges per gather (16 B/lane dwordx4) ====================
// Lane layout in fma phase: g=lane>>3 picks edge j+g, head=lane&7 picks the
// 16B head chunk. Weights in LDS [head*68+edge] (<=2-way banks). Final
// combine: shfl_xor over masks 8/16/32 (lanes sharing a head). Padded edges
// have w==0 in LDS -> contribute exactly 0.

#define G64(SUF, JB)                                                          \
    int sv##SUF = __builtin_amdgcn_ds_bpermute((JB) * 4 + g4, sv);            \
    float w##SUF = wb[(JB) + wofs];                                           \
    uint4 hv##SUF =                                                           \
        *(const uint4*)(gbase + (size_t)(unsigned)sv##SUF + hoff);

#define FMA8(SUF, LS)                                                         \
    LS;                                                                       \
    acc0 = fmaf(w##SUF, __uint_as_float(hv##SUF.x << 16), acc0);              \
    acc1 = fmaf(w##SUF, __uint_as_float(hv##SUF.x & 0xFFFF0000u), acc1);      \
    acc2 = fmaf(w##SUF, __uint_as_float(hv##SUF.y << 16), acc2);              \
    acc3 = fmaf(w##SUF, __uint_as_float(hv##SUF.y & 0xFFFF0000u), acc3);      \
    acc4 = fmaf(w##SUF, __uint_as_float(hv##SUF.z << 16), acc4);              \
    acc5 = fmaf(w##SUF, __uint_as_float(hv##SUF.z & 0xFFFF0000u), acc5);      \
    acc6 = fmaf(w##SUF, __uint_as_float(hv##SUF.w << 16), acc6);              \
    acc7 = fmaf(w##SUF, __uint_as_float(hv##SUF.w & 0xFFFF0000u), acc7);

__global__ __launch_bounds__(256) void aggr64_k(
    const char* __restrict__ hrec, const float* __restrict__ asb,
    const float* __restrict__ adb, const int* __restrict__ row_ptr,
    const int* __restrict__ csr_src, const float* __restrict__ bias,
    float* __restrict__ out, int N) {
    __shared__ float wlds[4 * 544];  // 4 waves x 8 heads x 68
    int wave = threadIdx.x >> 6;
    int node = blockIdx.x * 4 + wave;
    if (node >= N) return;
    int lane = threadIdx.x & 63;
    const char* gbase = hrec;
    float* wb = wlds + wave * 544;
    int g4 = (lane >> 3) * 4;                      // bpermute byte addr part
    int hoff = (lane & 7) * 16;                    // byte offset in record
    int wofs = (lane & 7) * 68 + (lane >> 3);      // w read offset
    int beg = row_ptr[node], end = row_ptr[node + 1];
    float4 adv0 = *(const float4*)(adb + (size_t)node * 8);
    float4 adv1 = *(const float4*)(adb + (size_t)node * 8 + 4);
    float acc0 = 0.f, acc1 = 0.f, acc2 = 0.f, acc3 = 0.f;
    float acc4 = 0.f, acc5 = 0.f, acc6 = 0.f, acc7 = 0.f;
    float lpart = 0.f;
    for (int i0 = beg; i0 < end; i0 += 64) {
        int tail = end - i0;
        int sv = csr_src[i0 + (lane < tail ? lane : 0)];  // byte offset s<<7
        int cnt = tail < 64 ? tail : 64;
        // ---- weight phase: this lane's edge, all 8 heads ----
        {
            const float* asp =
                (const float*)((const char*)asb + (((unsigned)sv) >> 2));
            float4 s0 = *(const float4*)asp;
            float4 s1 = *(const float4*)(asp + 4);
            float w0 = s0.x + adv0.x; w0 = fmaxf(w0, NEG_SLOPE * w0); w0 = fexp2(w0);
            float w1 = s0.y + adv0.y; w1 = fmaxf(w1, NEG_SLOPE * w1); w1 = fexp2(w1);
            float w2 = s0.z + adv0.z; w2 = fmaxf(w2, NEG_SLOPE * w2); w2 = fexp2(w2);
            float w3 = s0.w + adv0.w; w3 = fmaxf(w3, NEG_SLOPE * w3); w3 = fexp2(w3);
            float w4 = s1.x + adv1.x; w4 = fmaxf(w4, NEG_SLOPE * w4); w4 = fexp2(w4);
            float w5 = s1.y + adv1.y; w5 = fmaxf(w5, NEG_SLOPE * w5); w5 = fexp2(w5);
            float w6 = s1.z + adv1.z; w6 = fmaxf(w6, NEG_SLOPE * w6); w6 = fexp2(w6);
            float w7 = s1.w + adv1.w; w7 = fmaxf(w7, NEG_SLOPE * w7); w7 = fexp2(w7);
            if (lane >= cnt) {  // zero-pad
                w0 = 0.f; w1 = 0.f; w2 = 0.f; w3 = 0.f;
                w4 = 0.f; w5 = 0.f; w6 = 0.f; w7 = 0.f;
            }
            wb[lane]          = w0;
            wb[68 + lane]     = w1;
            wb[2 * 68 + lane] = w2;
            wb[3 * 68 + lane] = w3;
            wb[4 * 68 + lane] = w4;
            wb[5 * 68 + lane] = w5;
            wb[6 * 68 + lane] = w6;
            wb[7 * 68 + lane] = w7;
        }
        // ---- fma phase: 8 edges per gather (lpart += w, per subset) ----
        int j = 0;
        for (; j + 32 <= cnt; j += 32) {
            G64(A, j) G64(B, j + 8) G64(C, j + 16) G64(D, j + 24)
            FMA8(A, lpart += wA) FMA8(B, lpart += wB)
            FMA8(C, lpart += wC) FMA8(D, lpart += wD)
        }
        for (; j < cnt; j += 8) {
            G64(A, j)
            FMA8(A, lpart += wA)
        }
    }
    // combine the 8 edge-subsets per head (lanes differing in bits 3..5)
    #pragma unroll
    for (int m = 8; m <= 32; m <<= 1) {
        acc0 += __shfl_xor(acc0, m);
        acc1 += __shfl_xor(acc1, m);
        acc2 += __shfl_xor(acc2, m);
        acc3 += __shfl_xor(acc3, m);
        acc4 += __shfl_xor(acc4, m);
        acc5 += __shfl_xor(acc5, m);
        acc6 += __shfl_xor(acc6, m);
        acc7 += __shfl_xor(acc7, m);
        lpart += __shfl_xor(lpart, m);
    }
    if (lane < 8) {  // lane = head; writes channels head*8..head*8+7
        float denom = lpart + 1e-16f;
        const float4 b0 = *(const float4*)(bias + lane * 8);
        const float4 b1 = *(const float4*)(bias + lane * 8 + 4);
        float4 o0, o1;
        o0.x = acc0 / denom + b0.x;
        o0.y = acc1 / denom + b0.y;
        o0.z = acc2 / denom + b0.z;
        o0.w = acc3 / denom + b0.w;
        o1.x = acc4 / denom + b1.x;
        o1.y = acc5 / denom + b1.y;
        o1.z = acc6 / denom + b1.z;
        o1.w = acc7 / denom + b1.w;
        float* op = out + (size_t)node * 64 + lane * 8;
        *(float4*)op = o0;
        *(float4*)(op + 4) = o1;
    }
}

// ======= aggr40: 8 edges per gather; 5 active 8-ch chunks ==================
// l comes from the weight phase (per-lane own edge, full-wave reduce).

#define G40(SUF, JB)                                                          \
    int sv##SUF = __builtin_amdgcn_ds_bpermute((JB) * 4 + g4, sv);            \
    float w##SUF = wb[(JB) + gof];                                            \
    uint4 hv##SUF =                                                           \
        *(const uint4*)(gbase + (size_t)(unsigned)sv##SUF + hoff);

__global__ __launch_bounds__(256) void aggr40_k(
    const char* __restrict__ rec40, const float* __restrict__ adb,
    const int* __restrict__ row_ptr, const int* __restrict__ csr_src,
    const float* __restrict__ bias, float* __restrict__ out, int N) {
    __shared__ float wlds[4 * 104];  // per wave: 64 w + 40 epi
    int wave = threadIdx.x >> 6;
    int node = blockIdx.x * 4 + wave;
    if (node >= N) return;
    int lane = threadIdx.x & 63;
    const char* gbase = rec40;
    float* wb = wlds + wave * 104;
    float* epi = wb + 64;
    int g4 = (lane >> 3) * 4;
    int sub = lane & 7;
    int hoff = (sub < 5 ? sub : 0) * 16;
    int gof = lane >> 3;
    int beg = row_ptr[node], end = row_ptr[node + 1];
    float ad = adb[node];
    float acc0 = 0.f, acc1 = 0.f, acc2 = 0.f, acc3 = 0.f;
    float acc4 = 0.f, acc5 = 0.f, acc6 = 0.f, acc7 = 0.f;
    float lpart = 0.f;
    for (int i0 = beg; i0 < end; i0 += 64) {
        int tail = end - i0;
        int sv = csr_src[i0 + (lane < tail ? lane : 0)];  // byte offset s<<7
        int cnt = tail < 64 ? tail : 64;
        // ---- weight phase: lane computes its own edge's weight ----
        float as = *(const float*)(rec40 + (size_t)(unsigned)sv + 80);
        float v = as + ad;
        v = fmaxf(v, NEG_SLOPE * v);
        float wv = fexp2(v);
        wv = (lane < cnt) ? wv : 0.f;
        lpart += wv;
        wb[lane] = wv;
        // ---- fma phase: 8 edges per gather (w already counted in lpart) ----
        int j = 0;
        for (; j + 32 <= cnt; j += 32) {
            G40(A, j) G40(B, j + 8) G40(C, j + 16) G40(D, j + 24)
            FMA8(A, ) FMA8(B, ) FMA8(C, ) FMA8(D, )
        }
        for (; j < cnt; j += 8) {
            G40(A, j)
            FMA8(A, )
        }
    }
    // reduce acc over the 8 edge-subsets (lanes sharing sub)
    #pragma unroll
    for (int m = 8; m <= 32; m <<= 1) {
        acc0 += __shfl_xor(acc0, m);
        acc1 += __shfl_xor(acc1, m);
        acc2 += __shfl_xor(acc2, m);
        acc3 += __shfl_xor(acc3, m);
        acc4 += __shfl_xor(acc4, m);
        acc5 += __shfl_xor(acc5, m);
        acc6 += __shfl_xor(acc6, m);
        acc7 += __shfl_xor(acc7, m);
    }
    // l: full-wave reduce of weight-phase partials
    #pragma unroll
    for (int off = 32; off > 0; off >>= 1) lpart += __shfl_xor(lpart, off);
    float l = lpart;
    // redistribute: lanes 0..4 (g==0, sub<5) hold sums for channels sub*8+k
    if (lane < 5) {
        *(float4*)&epi[lane * 8] = make_float4(acc0, acc1, acc2, acc3);
        *(float4*)&epi[lane * 8 + 4] = make_float4(acc4, acc5, acc6, acc7);
    }
    float accv = (lane < 40) ? epi[lane] : 0.f;
    // fused bias + log_softmax over the 40 class lanes
    float val = accv / (l + 1e-16f) + ((lane < 40) ? bias[lane] : 0.f);
    float mval = (lane < 40) ? val : -1e30f;
    #pragma unroll
    for (int off = 32; off > 0; off >>= 1)
        mval = fmaxf(mval, __shfl_xor(mval, off));
    float ex = (lane < 40) ? __expf(val - mval) : 0.f;
    #pragma unroll
    for (int off = 32; off > 0; off >>= 1) ex += __shfl_xor(ex, off);
    if (lane < 40)
        out[(size_t)node * 40 + lane] = val - mval - __logf(ex);
}

// =================== launch ===================

extern "C" void kernel_launch(void* const* d_in, const int* in_sizes, int n_in,
                              void* d_out, int out_size, void* d_ws,
                              size_t ws_size, hipStream_t stream) {
    const float* features = (const float*)d_in[0];
    const int* edge_index = (const int*)d_in[1];
    const float* W0 = (const float*)d_in[2];
    const float* as0 = (const float*)d_in[3];
    const float* ad0 = (const float*)d_in[4];
    const float* b0 = (const float*)d_in[5];
    const float* W1 = (const float*)d_in[6];
    const float* as1 = (const float*)d_in[7];
    const float* ad1 = (const float*)d_in[8];
    const float* b1 = (const float*)d_in[9];
    const float* W2 = (const float*)d_in[10];
    const float* as2 = (const float*)d_in[11];
    const float* ad2 = (const float*)d_in[12];
    const float* b2 = (const float*)d_in[13];

    int N = in_sizes[0] / 256;
    int E = in_sizes[1] / 2;
    int Etot = E + N;
    int nbuck = (N + 127) >> 7;  // 128-node buckets (<= MAXBUCK)
    const int* srcs = edge_index;
    const int* dsts = edge_index + E;

    // workspace layout
    float* ws = (float*)d_ws;
    float* Hbuf = ws;                              // N*64 floats (pairs scratch)
    float* Abuf = Hbuf + (size_t)N * 64;           // N*64 floats
    float* adb  = Abuf + (size_t)N * 64;           // N*8
    float* asb  = adb + (size_t)N * 8;             // N*8
    char* hrec  = (char*)(asb + (size_t)N * 8);    // N*128 bytes
    int* row_ptr = (int*)(hrec + (size_t)N * 128); // N+1
    int* bcnt    = row_ptr + (N + 2);              // MAXBUCK
    int* bptrE   = bcnt + MAXBUCK;                 // MAXBUCK
    int* bcurE   = bptrE + MAXBUCK;                // MAXBUCK
    int* csr_src = bcurE + MAXBUCK;                // Etot
    int* bhist   = csr_src + Etot;                 // gSc * MAXBUCK
    int* pairs   = (int*)Hbuf;                     // scratch, dead before gemm

    const int B = 256;
    int gAg = (N + 3) / 4;
    int gGm = (N + 63) / 64;
    int gSc = (E + EPB - 1) / EPB;

    // ---------- CSR build (all atomic frontiers bucket-level) ----------
    (void)hipMemsetAsync(bcnt, 0, MAXBUCK * 4, stream);
    bucket_hist_k<<<gSc, 512, 0, stream>>>(dsts, bcnt, bhist, E, nbuck);
    bucket_scan_k<<<1, 512, 0, stream>>>(bcnt, bptrE, bcurE, nbuck);
    bscatter_k<<<gSc, 512, 0, stream>>>(srcs, dsts, bhist, bcurE, pairs, E,
                                        nbuck);
    bucket_sort_k<<<nbuck, B, 0, stream>>>(pairs, bptrE, bcurE, row_ptr,
                                           csr_src, N, Etot);

    // ---------------- layer 0 ----------------
    gemm_pack8_k<256><<<gGm, B, 0, stream>>>(features, W0, as0, ad0, hrec,
                                             asb, adb, N);
    aggr64_k<<<gAg, B, 0, stream>>>(hrec, asb, adb, row_ptr, csr_src, b0,
                                    Abuf, N);

    // ---------------- layer 1 ----------------
    gemm_pack8_k<64><<<gGm, B, 0, stream>>>(Abuf, W1, as1, ad1, hrec, asb,
                                            adb, N);
    aggr64_k<<<gAg, B, 0, stream>>>(hrec, asb, adb, row_ptr, csr_src, b1,
                                    Abuf, N);

    // ---------------- layer 2 ----------------
    gemm_pack40_k<<<gGm, B, 0, stream>>>(Abuf, W2, as2, ad2, hrec, adb, N);
    aggr40_k<<<gAg, B, 0, stream>>>(hrec, adb, row_ptr, csr_src, b2,
                                    (float*)d_out, N);
}